// Round 10
// baseline (328.491 us; speedup 1.0000x reference)
//
#include <hip/hip_runtime.h>
#include <hip/hip_fp16.h>
#include <stdint.h>

#define HH 8
#define CC 32
#define HC 256   // H*C
#define FF 128
#define NEG 0.2f
#define LNEPS 1e-5f

typedef __attribute__((ext_vector_type(8))) short bf16x8;
typedef __attribute__((ext_vector_type(4))) float f32x4;
typedef unsigned short u16;

// ---------- helpers ----------
__device__ inline unsigned bf16r(float f) {           // round-to-nearest-even bf16
  unsigned u = __float_as_uint(f);
  return (u + 0x7fffu + ((u >> 16) & 1u)) >> 16;
}
__device__ inline float bflo(unsigned w) { return __uint_as_float(w << 16); }
__device__ inline float bfhi(unsigned w) { return __uint_as_float(w & 0xffff0000u); }
__device__ inline float leaky(float v) { return v >= 0.f ? v : NEG * v; }
__device__ inline float h2f(unsigned hbits) {
  return __half2float(__ushort_as_half((unsigned short)hbits));
}
__device__ inline u16 f2h(float f) {
  return __half_as_ushort(__float2half(f));
}
// byte extract -> float (v_cvt_f32_ubyte0..3)
__device__ inline float ub0(unsigned w) { return (float)(w & 0xffu); }
__device__ inline float ub1(unsigned w) { return (float)((w >> 8) & 0xffu); }
__device__ inline float ub2(unsigned w) { return (float)((w >> 16) & 0xffu); }
__device__ inline float ub3(unsigned w) { return (float)(w >> 24); }

// ---------- KLAYOUT: repack weights into MFMA B-fragment layout (bf16) ----------
__global__ __launch_bounds__(256) void klayout(
    const float* __restrict__ W, const float* __restrict__ atts,
    const float* __restrict__ attd, const float* __restrict__ w1,
    const float* __restrict__ w2,
    u16* __restrict__ Wb, u16* __restrict__ Zb,
    u16* __restrict__ V1b, u16* __restrict__ V2b)
{
  int t = threadIdx.x;
  for (int i = t; i < 16 * 512; i += 256) {        // Wb: W_gat [32,256]
    int j = i & 7, l = (i >> 3) & 63, nb = i >> 9;
    int k = 8 * (l >> 4) + j, c = 16 * nb + (l & 15);
    Wb[i] = (u16)bf16r(W[k * HC + c]);
  }
  for (int i = t; i < 8 * 512; i += 256) {         // Zb: [256,16] = [atts|attd] blockdiag
    int j = i & 7, l = (i >> 3) & 63, kb = i >> 9;
    int k = 32 * kb + 8 * (l >> 4) + j;
    int tc = l & 15;
    float v = 0.f;
    if (tc < 8)  { if ((k >> 5) == tc)     v = atts[tc * 32 + (k & 31)]; }
    else         { if ((k >> 5) == tc - 8) v = attd[(tc - 8) * 32 + (k & 31)]; }
    Zb[i] = (u16)bf16r(v);
  }
  for (int i = t; i < 8 * 512; i += 256) {         // V1b: w1 [32,128]
    int j = i & 7, l = (i >> 3) & 63, nb = i >> 9;
    int k = 8 * (l >> 4) + j, c = 16 * nb + (l & 15);
    V1b[i] = (u16)bf16r(w1[k * FF + c]);
  }
  for (int i = t; i < 8 * 512; i += 256) {         // V2b: w2 [128,32]
    int j = i & 7, l = (i >> 3) & 63, kn = i >> 9;
    int kb = kn >> 1, nb2 = kn & 1;
    int k = 32 * kb + 8 * (l >> 4) + j, c = 16 * nb2 + (l & 15);
    V2b[i] = (u16)bf16r(w2[k * CC + c]);
  }
}

// ---------- K1M: MFMA xp=x@W -> int8 rows + packed (bf16 a_src|fp16 scale) + a_dst
//             + fused histogram that ALSO emits per-edge rank (dst | rank<<17) ----------
__global__ __launch_bounds__(256) void k1m(
    const float* __restrict__ x, const u16* __restrict__ Wb,
    const u16* __restrict__ Zb, const int* __restrict__ ei,
    unsigned* __restrict__ xq8, unsigned* __restrict__ ascp,
    float* __restrict__ a_d, int* __restrict__ deg,
    unsigned* __restrict__ dstr, int n, int e, int nbc)
{
  if ((int)blockIdx.x >= nbc) {                    // histogram + rank role
    int i = ((int)blockIdx.x - nbc) * 1024 + (int)threadIdx.x * 4;
    if (i >= e) return;
    const int* dst = ei + e;
    if (i + 3 < e) {
      int4 d4 = *(const int4*)(dst + i);
      unsigned r0 = (unsigned)atomicAdd(&deg[d4.x], 1);
      unsigned r1 = (unsigned)atomicAdd(&deg[d4.y], 1);
      unsigned r2 = (unsigned)atomicAdd(&deg[d4.z], 1);
      unsigned r3 = (unsigned)atomicAdd(&deg[d4.w], 1);
      uint4 o;
      o.x = (unsigned)d4.x | (r0 << 17);
      o.y = (unsigned)d4.y | (r1 << 17);
      o.z = (unsigned)d4.z | (r2 << 17);
      o.w = (unsigned)d4.w | (r3 << 17);
      *(uint4*)(dstr + i) = o;
    } else {
      for (int k = 0; k < 4 && i + k < e; ++k) {
        int d = dst[i + k];
        unsigned r = (unsigned)atomicAdd(&deg[d], 1);
        dstr[i + k] = (unsigned)d | (r << 17);
      }
    }
    return;
  }
  __shared__ u16 lt[4][16 * 264];                  // per-wave [16 rows][264 halfs]
  __shared__ float lsc[4][16][8];                  // per-wave rinv = 127/rowmax
  int wid = threadIdx.x >> 6, lane = threadIdx.x & 63;
  int q = lane & 15, g = lane >> 4;
  long node0 = (long)((int)blockIdx.x * 4 + wid) * 16;
  if (node0 + 16 > n) node0 = n - 16;              // overlap tail: duplicate identical writes
  u16* L = lt[wid];

  // A-frag: x[node0+q][8g..8g+7] -> bf16
  const float* xr = x + (node0 + q) * CC + 8 * g;
  float4 xa = *(const float4*)xr, xb = *(const float4*)(xr + 4);
  bf16x8 af;
  af[0] = (short)bf16r(xa.x); af[1] = (short)bf16r(xa.y);
  af[2] = (short)bf16r(xa.z); af[3] = (short)bf16r(xa.w);
  af[4] = (short)bf16r(xb.x); af[5] = (short)bf16r(xb.y);
  af[6] = (short)bf16r(xb.z); af[7] = (short)bf16r(xb.w);

#pragma unroll
  for (int nb = 0; nb < 16; ++nb) {
    bf16x8 bf = *(const bf16x8*)(Wb + nb * 512 + lane * 8);
    f32x4 acc = {0.f, 0.f, 0.f, 0.f};
    acc = __builtin_amdgcn_mfma_f32_16x16x32_bf16(af, bf, acc, 0, 0, 0);
    int col = 16 * nb + q;
#pragma unroll
    for (int r = 0; r < 4; ++r)
      L[(4 * g + r) * 264 + col] = (u16)bf16r(acc[r]);
  }
  __syncthreads();

  // a_src/a_dst: [16 nodes,256] x [256,16] via 8 chained mfma
  f32x4 az = {0.f, 0.f, 0.f, 0.f};
#pragma unroll
  for (int kb = 0; kb < 8; ++kb) {
    bf16x8 a2 = *(const bf16x8*)(L + q * 264 + kb * 32 + g * 8);
    bf16x8 zb = *(const bf16x8*)(Zb + kb * 512 + lane * 8);
    az = __builtin_amdgcn_mfma_f32_16x16x32_bf16(a2, zb, az, 0, 0, 0);
  }
  int hq = q & 7;
  u16* ascp16 = (u16*)ascp;
  if (q < 8) {                                     // a_src -> ascp lo16 (bf16)
#pragma unroll
    for (int r = 0; r < 4; ++r)
      ascp16[((node0 + 4 * g + r) * HH + hq) * 2] = (u16)bf16r(az[r]);
  } else {                                         // a_dst (fp32)
#pragma unroll
    for (int r = 0; r < 4; ++r)
      a_d[(node0 + 4 * g + r) * HH + hq] = az[r];
  }

  // per-(row,head) absmax -> fp16 scale (ascp hi16) + rinv (LDS)
#pragma unroll
  for (int t2 = 0; t2 < 2; ++t2) {
    int task = t2 * 64 + lane;                     // 128 tasks
    int r = task >> 3, h = task & 7;
    const unsigned* p = (const unsigned*)(L + r * 264 + h * 32);
    float mx = 0.f;
#pragma unroll
    for (int i = 0; i < 16; ++i) {
      unsigned w = p[i];
      mx = fmaxf(mx, fmaxf(fabsf(bflo(w)), fabsf(bfhi(w))));
    }
    float rinv = (mx > 0.f) ? 127.f / mx : 0.f;
    ascp16[((node0 + r) * HH + h) * 2 + 1] = f2h(mx * (1.f / 127.f));
    lsc[wid][r][h] = rinv;
  }
  __syncthreads();

  // int8 encode + store: 16 rows x 64 dwords, 16 dwords per lane
#pragma unroll
  for (int i = 0; i < 16; ++i) {
    int d = i * 64 + lane;
    int r = d >> 6, c = d & 63;                    // c: dword within 256B row
    int h = c >> 3;
    float rv = lsc[wid][r][h];
    const unsigned* p = (const unsigned*)(L + r * 264) + (c << 1);
    unsigned w0 = p[0], w1 = p[1];
    int q0 = __float2int_rn(bflo(w0) * rv);
    int q1 = __float2int_rn(bfhi(w0) * rv);
    int q2 = __float2int_rn(bflo(w1) * rv);
    int q3 = __float2int_rn(bfhi(w1) * rv);
    q0 = min(max(q0, -127), 127) + 128;
    q1 = min(max(q1, -127), 127) + 128;
    q2 = min(max(q2, -127), 127) + 128;
    q3 = min(max(q3, -127), 127) + 128;
    unsigned pk = (unsigned)q0 | ((unsigned)q1 << 8) |
                  ((unsigned)q2 << 16) | ((unsigned)q3 << 24);
    xq8[(node0 + r) * 64 + c] = pk;
  }
}

// ---------- scan phase A ----------
__global__ __launch_bounds__(256) void kscanA(const int* __restrict__ deg,
                                              int* __restrict__ bsum, int n)
{
  __shared__ int ws[4];
  int t = threadIdx.x;
  int i = (int)blockIdx.x * 1024 + t * 4;
  int4 v = make_int4(0, 0, 0, 0);
  if (i + 3 < n) v = *(const int4*)(deg + i);
  else {
    if (i     < n) v.x = deg[i];
    if (i + 1 < n) v.y = deg[i + 1];
    if (i + 2 < n) v.z = deg[i + 2];
    if (i + 3 < n) v.w = deg[i + 3];
  }
  int s = v.x + v.y + v.z + v.w;
#pragma unroll
  for (int mask = 1; mask < 64; mask <<= 1) s += __shfl_xor(s, mask);
  if ((t & 63) == 0) ws[t >> 6] = s;
  __syncthreads();
  if (t == 0) bsum[blockIdx.x] = ws[0] + ws[1] + ws[2] + ws[3];
}

// ---------- scan phase B ----------
__global__ __launch_bounds__(1024) void kscanB(int* __restrict__ bsum, int nb)
{
  __shared__ int wsum[16];
  int t = threadIdx.x, lane = t & 63, wid = t >> 6;
  int v = (t < nb) ? bsum[t] : 0;
  int s = v;
#pragma unroll
  for (int d = 1; d < 64; d <<= 1) { int tt = __shfl_up(s, d); if (lane >= d) s += tt; }
  if (lane == 63) wsum[wid] = s;
  __syncthreads();
  if (wid == 0) {
    int w = (lane < 16) ? wsum[lane] : 0;
#pragma unroll
    for (int d = 1; d < 16; d <<= 1) { int tt = __shfl_up(w, d); if (lane >= d) w += tt; }
    if (lane < 16) wsum[lane] = w;
  }
  __syncthreads();
  int excl = s - v + ((wid > 0) ? wsum[wid - 1] : 0);
  if (t < nb) bsum[t] = excl;
}

// ---------- scan phase C ----------
__global__ __launch_bounds__(256) void kscanC(const int* __restrict__ deg,
                                              const int* __restrict__ bsum,
                                              int* __restrict__ offs, int n)
{
  __shared__ int ws[4];
  int t = threadIdx.x, lane = t & 63, wid = t >> 6;
  int i = (int)blockIdx.x * 1024 + t * 4;
  int4 v = make_int4(0, 0, 0, 0);
  if (i + 3 < n) v = *(const int4*)(deg + i);
  else {
    if (i     < n) v.x = deg[i];
    if (i + 1 < n) v.y = deg[i + 1];
    if (i + 2 < n) v.z = deg[i + 2];
    if (i + 3 < n) v.w = deg[i + 3];
  }
  int tsum = v.x + v.y + v.z + v.w;
  int s = tsum;
#pragma unroll
  for (int d = 1; d < 64; d <<= 1) { int tt = __shfl_up(s, d); if (lane >= d) s += tt; }
  if (lane == 63) ws[wid] = s;
  __syncthreads();
  if (t == 0) {
    int a = ws[0]; ws[0] = 0;
    int b = ws[1]; ws[1] = a; a += b;
    int c = ws[2]; ws[2] = a; a += c;
    ws[3] = a;
  }
  __syncthreads();
  int base = bsum[blockIdx.x] + ws[wid] + (s - tsum);
  if (i     < n) offs[i]     = base; base += v.x;
  if (i + 1 < n) offs[i + 1] = base; base += v.y;
  if (i + 2 < n) offs[i + 2] = base; base += v.z;
  if (i + 3 < n) offs[i + 3] = base;
}

// ---------- CSR scatter: rank-based, ATOMIC-FREE, dst-octant L2-local writes ----------
__global__ __launch_bounds__(256) void kscatter(
    const int* __restrict__ ei, const unsigned* __restrict__ dstr, int e,
    const int* __restrict__ offs, int* __restrict__ csr, int n)
{
  int oct = (int)blockIdx.x & 7;
  int nsub = (int)gridDim.x >> 3;
  int sub = (int)blockIdx.x >> 3;
  int nper = (n + 7) >> 3;
  int lo = oct * nper, hi = lo + nper;
  int stride = nsub << 10;
  for (int i = (sub * 256 + (int)threadIdx.x) * 4; i < e; i += stride) {
    if (i + 3 < e) {
      uint4 d4 = *(const uint4*)(dstr + i);
      int4 s4 = *(const int4*)(ei + i);
      int dx = d4.x & 0x1ffff, dy = d4.y & 0x1ffff,
          dz = d4.z & 0x1ffff, dw = d4.w & 0x1ffff;
      if (dx >= lo && dx < hi) csr[offs[dx] + (d4.x >> 17)] = s4.x;
      if (dy >= lo && dy < hi) csr[offs[dy] + (d4.y >> 17)] = s4.y;
      if (dz >= lo && dz < hi) csr[offs[dz] + (d4.z >> 17)] = s4.z;
      if (dw >= lo && dw < hi) csr[offs[dw] + (d4.w >> 17)] = s4.w;
    } else {
      for (int k = 0; k < 4 && i + k < e; ++k) {
        unsigned dv = dstr[i + k];
        int d = dv & 0x1ffff;
        if (d >= lo && d < hi) csr[offs[d] + (dv >> 17)] = ei[i + k];
      }
    }
  }
}

// ---------- KAGG: wave-per-node, flat-64 fixed-reference softmax + int8 gather ----------
// Fixed reference m = aself (defer-max): p = exp(alpha - aself), bounded (|alpha|<~10).
// Round of 64: lane=edge, loads full 32B ascp row; p/p*sc staged to LDS (bf16|bf16,
// stride 9 = conflict-free); inner loop (B layout: hb=lane>>3) reads wt + gathers xq8.
__global__ __launch_bounds__(256) void kagg(
    const int* __restrict__ csr, const int* __restrict__ offs,
    const int* __restrict__ deg,
    const unsigned* __restrict__ ascp, const float* __restrict__ a_d,
    const unsigned* __restrict__ xq8, float* __restrict__ og, int n)
{
  __shared__ unsigned lw[4][64 * 9];    // per-wave [edge][head] stride-9 staging
  int lane = threadIdx.x & 63;
  int wid  = threadIdx.x >> 6;
  int node = (int)blockIdx.x * 4 + wid;
  if (node >= n) return;
  unsigned* WT = lw[wid];
  int hb = lane >> 3;
  int doff = hb * 8 + (lane & 7);       // dword index within 64-dword (256B) row

  int start = offs[node];
  int dg = deg[node];

  // broadcast loads: node's a_d row (fp32 x8) and ascp row (8 dwords)
  const float4* adp = (const float4*)(a_d + (size_t)node * HH);
  float4 ad0 = adp[0], ad1 = adp[1];
  float ad[8] = {ad0.x, ad0.y, ad0.z, ad0.w, ad1.x, ad1.y, ad1.z, ad1.w};
  const uint4* asp = (const uint4*)(ascp + (size_t)node * HH);
  uint4 as0 = asp[0], as1 = asp[1];
  unsigned sw[8] = {as0.x, as0.y, as0.z, as0.w, as1.x, as1.y, as1.z, as1.w};
  float aself[8];
#pragma unroll
  for (int h = 0; h < 8; ++h) aself[h] = leaky(bflo(sw[h]) + ad[h]);

  float acc0 = 0.f, acc1 = 0.f, acc2 = 0.f, acc3 = 0.f;
  float osum = 0.f, dnacc = 0.f;

  for (int j0 = 0; j0 < dg; j0 += 64) {
    int cnt = min(64, dg - j0);
    int el = j0 + lane;
    bool valid = el < dg;
    int srcl = valid ? csr[start + el] : 0;
    const uint4* ap = (const uint4*)(ascp + (size_t)srcl * HH);
    uint4 a0 = ap[0], a1 = ap[1];
    unsigned aw[8] = {a0.x, a0.y, a0.z, a0.w, a1.x, a1.y, a1.z, a1.w};
#pragma unroll
    for (int h = 0; h < 8; ++h) {
      float al = leaky(bflo(aw[h]) + ad[h]);
      float p  = valid ? __expf(al - aself[h]) : 0.f;
      float pw = p * h2f(aw[h] >> 16);
      WT[lane * 9 + h] = bf16r(p) | (bf16r(pw) << 16);
    }
    // make this wave's LDS writes visible to its own cross-lane reads
    asm volatile("s_waitcnt lgkmcnt(0)" ::: "memory");
    __builtin_amdgcn_sched_barrier(0);
#pragma unroll 4
    for (int j = 0; j < cnt; ++j) {
      unsigned pp = WT[j * 9 + hb];
      int s = __shfl(srcl, j);
      unsigned w = xq8[(size_t)s * 64 + doff];
      float p = bflo(pp), wt = bfhi(pp);
      dnacc += p; osum += wt;
      acc0 = fmaf(ub0(w), wt, acc0);
      acc1 = fmaf(ub1(w), wt, acc1);
      acc2 = fmaf(ub2(w), wt, acc2);
      acc3 = fmaf(ub3(w), wt, acc3);
    }
  }

  // self loop: p = 1, weight = own scale (select sw[hb] statically)
  {
    unsigned s01 = (hb & 1) ? sw[1] : sw[0];
    unsigned s23 = (hb & 1) ? sw[3] : sw[2];
    unsigned s45 = (hb & 1) ? sw[5] : sw[4];
    unsigned s67 = (hb & 1) ? sw[7] : sw[6];
    s01 = (hb & 2) ? s23 : s01;
    s45 = (hb & 2) ? s67 : s45;
    unsigned swB = (hb & 4) ? s45 : s01;
    float wt = h2f(swB >> 16);
    unsigned w = xq8[(size_t)node * 64 + doff];
    dnacc += 1.f; osum += wt;
    acc0 = fmaf(ub0(w), wt, acc0);
    acc1 = fmaf(ub1(w), wt, acc1);
    acc2 = fmaf(ub2(w), wt, acc2);
    acc3 = fmaf(ub3(w), wt, acc3);
  }

  float corr = -128.f * osum;
  float inv = 0.125f / dnacc;
  acc0 = (acc0 + corr) * inv;
  acc1 = (acc1 + corr) * inv;
  acc2 = (acc2 + corr) * inv;
  acc3 = (acc3 + corr) * inv;
#pragma unroll
  for (int mask = 8; mask < 64; mask <<= 1) {
    acc0 += __shfl_xor(acc0, mask);
    acc1 += __shfl_xor(acc1, mask);
    acc2 += __shfl_xor(acc2, mask);
    acc3 += __shfl_xor(acc3, mask);
  }
  if (lane < 8) {
    *(float4*)(og + (size_t)node * CC + lane * 4) =
      make_float4(acc0, acc1, acc2, acc3);
  }
}

// ---------- K5M: MFMA tail — LN1 + FFN(mfma) + LN2 ----------
__global__ __launch_bounds__(256) void k5m(
    const float* __restrict__ og, const float* __restrict__ x,
    const float* __restrict__ bg,
    const u16* __restrict__ V1b, const u16* __restrict__ V2b,
    const float* __restrict__ b1, const float* __restrict__ b2,
    const float* __restrict__ g1, const float* __restrict__ be1,
    const float* __restrict__ g2, const float* __restrict__ be2,
    float* __restrict__ out, int n)
{
  __shared__ u16   lh[4][16 * 40];
  __shared__ u16   lf[4][16 * 136];
  __shared__ float lo[4][16 * 36];
  int wid = threadIdx.x >> 6, lane = threadIdx.x & 63;
  int q = lane & 15, g = lane >> 4;
  long node0 = (long)((int)blockIdx.x * 4 + wid) * 16;
  if (node0 + 16 > n) node0 = n - 16;
  u16* LH = lh[wid]; u16* LF = lf[wid]; float* LO = lo[wid];

  {
    int row = lane >> 2, off = (lane & 3) * 8;
    const float* o8 = og + (node0 + row) * CC + off;
    const float* x8 = x  + (node0 + row) * CC + off;
    float4 a0 = *(const float4*)o8, a1 = *(const float4*)(o8 + 4);
    float4 c0 = *(const float4*)x8, c1 = *(const float4*)(x8 + 4);
    float4 bg0 = *(const float4*)(bg + off), bg1 = *(const float4*)(bg + off + 4);
    float4 s0 = make_float4(a0.x + c0.x + bg0.x, a0.y + c0.y + bg0.y,
                            a0.z + c0.z + bg0.z, a0.w + c0.w + bg0.w);
    float4 s1 = make_float4(a1.x + c1.x + bg1.x, a1.y + c1.y + bg1.y,
                            a1.z + c1.z + bg1.z, a1.w + c1.w + bg1.w);
    *(float4*)(LO + row * 36 + off)     = s0;
    *(float4*)(LO + row * 36 + off + 4) = s1;
  }
  __syncthreads();

  float hv[32];
  if (lane < 16) {
#pragma unroll
    for (int i = 0; i < 8; ++i) {
      float4 t = *(const float4*)(LO + q * 36 + i * 4);
      hv[4*i] = t.x; hv[4*i+1] = t.y; hv[4*i+2] = t.z; hv[4*i+3] = t.w;
    }
    float mu = 0.f;
#pragma unroll
    for (int c = 0; c < 32; ++c) mu += hv[c];
    mu *= (1.f / 32.f);
    float var = 0.f;
#pragma unroll
    for (int c = 0; c < 32; ++c) { float t = hv[c] - mu; var = fmaf(t, t, var); }
    float rs = rsqrtf(var * (1.f / 32.f) + LNEPS);
#pragma unroll
    for (int c = 0; c < 32; ++c) hv[c] = (hv[c] - mu) * rs * g1[c] + be1[c];
    uint* dst = (uint*)(LH + q * 40);
#pragma unroll
    for (int i = 0; i < 16; ++i)
      dst[i] = bf16r(hv[2*i]) | (bf16r(hv[2*i+1]) << 16);
  }
  __syncthreads();

  bf16x8 ah = *(const bf16x8*)(LH + q * 40 + g * 8);
#pragma unroll
  for (int nb = 0; nb < 8; ++nb) {
    bf16x8 v1 = *(const bf16x8*)(V1b + nb * 512 + lane * 8);
    f32x4 acc = {0.f, 0.f, 0.f, 0.f};
    acc = __builtin_amdgcn_mfma_f32_16x16x32_bf16(ah, v1, acc, 0, 0, 0);
    int col = 16 * nb + q;
    float bias = b1[col];
#pragma unroll
    for (int r = 0; r < 4; ++r) {
      float f = fmaxf(acc[r] + bias, 0.f);
      LF[(4 * g + r) * 136 + col] = (u16)bf16r(f);
    }
  }
  __syncthreads();

  f32x4 a20 = {0.f, 0.f, 0.f, 0.f}, a21 = {0.f, 0.f, 0.f, 0.f};
#pragma unroll
  for (int kb = 0; kb < 4; ++kb) {
    bf16x8 af2 = *(const bf16x8*)(LF + q * 136 + kb * 32 + g * 8);
    bf16x8 v20 = *(const bf16x8*)(V2b + (kb * 2 + 0) * 512 + lane * 8);
    bf16x8 v21 = *(const bf16x8*)(V2b + (kb * 2 + 1) * 512 + lane * 8);
    a20 = __builtin_amdgcn_mfma_f32_16x16x32_bf16(af2, v20, a20, 0, 0, 0);
    a21 = __builtin_amdgcn_mfma_f32_16x16x32_bf16(af2, v21, a21, 0, 0, 0);
  }
  __syncthreads();
#pragma unroll
  for (int r = 0; r < 4; ++r) {
    LO[(4 * g + r) * 36 + q]      = a20[r];
    LO[(4 * g + r) * 36 + 16 + q] = a21[r];
  }
  __syncthreads();

  if (lane < 16) {
    float ov[32];
#pragma unroll
    for (int i = 0; i < 8; ++i) {
      float4 t = *(const float4*)(LO + q * 36 + i * 4);
      ov[4*i] = t.x; ov[4*i+1] = t.y; ov[4*i+2] = t.z; ov[4*i+3] = t.w;
    }
#pragma unroll
    for (int c = 0; c < 32; ++c) ov[c] += b2[c] + hv[c];
    float mu2 = 0.f;
#pragma unroll
    for (int c = 0; c < 32; ++c) mu2 += ov[c];
    mu2 *= (1.f / 32.f);
    float var2 = 0.f;
#pragma unroll
    for (int c = 0; c < 32; ++c) { float t = ov[c] - mu2; var2 = fmaf(t, t, var2); }
    float rs2 = rsqrtf(var2 * (1.f / 32.f) + LNEPS);
    float* op = out + (node0 + q) * CC;
#pragma unroll
    for (int i = 0; i < 8; ++i) {
      float4 o;
      o.x = (ov[4*i]   - mu2) * rs2 * g2[4*i]   + be2[4*i];
      o.y = (ov[4*i+1] - mu2) * rs2 * g2[4*i+1] + be2[4*i+1];
      o.z = (ov[4*i+2] - mu2) * rs2 * g2[4*i+2] + be2[4*i+2];
      o.w = (ov[4*i+3] - mu2) * rs2 * g2[4*i+3] + be2[4*i+3];
      *(float4*)(op + i * 4) = o;
    }
  }
}

// ---------- launch ----------
extern "C" void kernel_launch(void* const* d_in, const int* in_sizes, int n_in,
                              void* d_out, int out_size, void* d_ws, size_t ws_size,
                              hipStream_t stream)
{
  const float* x    = (const float*)d_in[0];
  const int*   ei   = (const int*)d_in[1];
  const float* W    = (const float*)d_in[2];
  const float* atts = (const float*)d_in[3];
  const float* attd = (const float*)d_in[4];
  const float* bg   = (const float*)d_in[5];
  const float* w1   = (const float*)d_in[6];
  const float* b1   = (const float*)d_in[7];
  const float* w2   = (const float*)d_in[8];
  const float* b2   = (const float*)d_in[9];
  const float* g1   = (const float*)d_in[10];
  const float* be1  = (const float*)d_in[11];
  const float* g2   = (const float*)d_in[12];
  const float* be2  = (const float*)d_in[13];

  int n = in_sizes[0] / CC;
  int e = in_sizes[1] / 2;

  uint8_t* ws = (uint8_t*)d_ws;
  size_t o = 0;
  unsigned* xq8 = (unsigned*)(ws + o); o += (size_t)n * 256;   // int8 rows, 256B/node
  unsigned* ascp = (unsigned*)(ws + o); o += (size_t)n * HH * 4; // bf16 a_src|fp16 scale
  float* a_d = (float*)(ws + o); o += (size_t)n * HH * 4;
  float* og  = (float*)(ws + o); o += (size_t)n * CC * 4;
  int* deg    = (int*)(ws + o); o += (size_t)n * 4;
  int* offs   = (int*)(ws + o); o += (size_t)n * 4;
  unsigned* dstr = (unsigned*)(ws + o); o += (size_t)e * 4;
  int* csr    = (int*)(ws + o); o += (size_t)e * 4;
  int* bsum   = (int*)(ws + o); o += 4096;
  u16* Wb  = (u16*)(ws + o); o += 16 * 512 * 2;
  u16* Zb  = (u16*)(ws + o); o += 8 * 512 * 2;
  u16* V1b = (u16*)(ws + o); o += 8 * 512 * 2;
  u16* V2b = (u16*)(ws + o); o += 8 * 512 * 2;

  (void)hipMemsetAsync(deg, 0, (size_t)n * 4, stream);

  int nwaves = (n + 15) / 16;
  int nbc   = (nwaves + 3) / 4;
  int nb_e4 = (e + 1023) / 1024;
  int nb_s  = (n + 1023) / 1024;

  klayout <<<1, 256, 0, stream>>>(W, atts, attd, w1, w2, Wb, Zb, V1b, V2b);
  k1m     <<<nbc + nb_e4, 256, 0, stream>>>(x, Wb, Zb, ei, xq8, ascp, a_d, deg,
                                            dstr, n, e, nbc);
  kscanA  <<<nb_s, 256, 0, stream>>>(deg, bsum, n);
  kscanB  <<<1, 1024, 0, stream>>>(bsum, nb_s);
  kscanC  <<<nb_s, 256, 0, stream>>>(deg, bsum, offs, n);
  kscatter<<<512, 256, 0, stream>>>(ei, dstr, e, offs, csr, n);
  kagg    <<<(n + 3) / 4, 256, 0, stream>>>(csr, offs, deg, ascp, a_d, xq8, og, n);
  k5m     <<<nbc, 256, 0, stream>>>(og, x, bg, V1b, V2b, b1, b2, g1, be1, g2, be2,
                                    (float*)d_out, n);
}

// Round 12
// 262.530 us; speedup vs baseline: 1.2513x; 1.2513x over previous
//
#include <hip/hip_runtime.h>
#include <hip/hip_fp16.h>
#include <stdint.h>

#define HH 8
#define CC 32
#define HC 256   // H*C
#define FF 128
#define NEG 0.2f
#define LNEPS 1e-5f

typedef __attribute__((ext_vector_type(8))) short bf16x8;
typedef __attribute__((ext_vector_type(4))) float f32x4;
typedef unsigned short u16;

// ---------- helpers ----------
__device__ inline unsigned bf16r(float f) {           // round-to-nearest-even bf16
  unsigned u = __float_as_uint(f);
  return (u + 0x7fffu + ((u >> 16) & 1u)) >> 16;
}
__device__ inline float bflo(unsigned w) { return __uint_as_float(w << 16); }
__device__ inline float bfhi(unsigned w) { return __uint_as_float(w & 0xffff0000u); }
__device__ inline float leaky(float v) { return v >= 0.f ? v : NEG * v; }
__device__ inline float h2f(unsigned hbits) {
  return __half2float(__ushort_as_half((unsigned short)hbits));
}
__device__ inline u16 f2h(float f) {
  return __half_as_ushort(__float2half(f));
}
// byte extract -> float (v_cvt_f32_ubyte0..3)
__device__ inline float ub0(unsigned w) { return (float)(w & 0xffu); }
__device__ inline float ub1(unsigned w) { return (float)((w >> 8) & 0xffu); }
__device__ inline float ub2(unsigned w) { return (float)((w >> 16) & 0xffu); }
__device__ inline float ub3(unsigned w) { return (float)(w >> 24); }

// ---------- KLAYOUT: repack weights into MFMA B-fragment layout (bf16) ----------
__global__ __launch_bounds__(256) void klayout(
    const float* __restrict__ W, const float* __restrict__ atts,
    const float* __restrict__ attd, const float* __restrict__ w1,
    const float* __restrict__ w2,
    u16* __restrict__ Wb, u16* __restrict__ Zb,
    u16* __restrict__ V1b, u16* __restrict__ V2b)
{
  int t = threadIdx.x;
  for (int i = t; i < 16 * 512; i += 256) {        // Wb: W_gat [32,256]
    int j = i & 7, l = (i >> 3) & 63, nb = i >> 9;
    int k = 8 * (l >> 4) + j, c = 16 * nb + (l & 15);
    Wb[i] = (u16)bf16r(W[k * HC + c]);
  }
  for (int i = t; i < 8 * 512; i += 256) {         // Zb: [256,16] = [atts|attd] blockdiag
    int j = i & 7, l = (i >> 3) & 63, kb = i >> 9;
    int k = 32 * kb + 8 * (l >> 4) + j;
    int tc = l & 15;
    float v = 0.f;
    if (tc < 8)  { if ((k >> 5) == tc)     v = atts[tc * 32 + (k & 31)]; }
    else         { if ((k >> 5) == tc - 8) v = attd[(tc - 8) * 32 + (k & 31)]; }
    Zb[i] = (u16)bf16r(v);
  }
  for (int i = t; i < 8 * 512; i += 256) {         // V1b: w1 [32,128]
    int j = i & 7, l = (i >> 3) & 63, nb = i >> 9;
    int k = 8 * (l >> 4) + j, c = 16 * nb + (l & 15);
    V1b[i] = (u16)bf16r(w1[k * FF + c]);
  }
  for (int i = t; i < 8 * 512; i += 256) {         // V2b: w2 [128,32]
    int j = i & 7, l = (i >> 3) & 63, kn = i >> 9;
    int kb = kn >> 1, nb2 = kn & 1;
    int k = 32 * kb + 8 * (l >> 4) + j, c = 16 * nb2 + (l & 15);
    V2b[i] = (u16)bf16r(w2[k * CC + c]);
  }
}

// ---------- K1M: MFMA xp=x@W -> int8 rows + packed (bf16 a_src|fp16 scale) + a_dst
//             + fused histogram that ALSO emits per-edge rank (dst | rank<<17) ----------
__global__ __launch_bounds__(256) void k1m(
    const float* __restrict__ x, const u16* __restrict__ Wb,
    const u16* __restrict__ Zb, const int* __restrict__ ei,
    unsigned* __restrict__ xq8, unsigned* __restrict__ ascp,
    float* __restrict__ a_d, int* __restrict__ deg,
    unsigned* __restrict__ dstr, int n, int e, int nbc)
{
  if ((int)blockIdx.x >= nbc) {                    // histogram + rank role
    int i = ((int)blockIdx.x - nbc) * 1024 + (int)threadIdx.x * 4;
    if (i >= e) return;
    const int* dst = ei + e;
    if (i + 3 < e) {
      int4 d4 = *(const int4*)(dst + i);
      unsigned r0 = (unsigned)atomicAdd(&deg[d4.x], 1);
      unsigned r1 = (unsigned)atomicAdd(&deg[d4.y], 1);
      unsigned r2 = (unsigned)atomicAdd(&deg[d4.z], 1);
      unsigned r3 = (unsigned)atomicAdd(&deg[d4.w], 1);
      uint4 o;
      o.x = (unsigned)d4.x | (r0 << 17);
      o.y = (unsigned)d4.y | (r1 << 17);
      o.z = (unsigned)d4.z | (r2 << 17);
      o.w = (unsigned)d4.w | (r3 << 17);
      *(uint4*)(dstr + i) = o;
    } else {
      for (int k = 0; k < 4 && i + k < e; ++k) {
        int d = dst[i + k];
        unsigned r = (unsigned)atomicAdd(&deg[d], 1);
        dstr[i + k] = (unsigned)d | (r << 17);
      }
    }
    return;
  }
  __shared__ u16 lt[4][16 * 264];                  // per-wave [16 rows][264 halfs]
  __shared__ float lsc[4][16][8];                  // per-wave rinv = 127/rowmax
  int wid = threadIdx.x >> 6, lane = threadIdx.x & 63;
  int q = lane & 15, g = lane >> 4;
  long node0 = (long)((int)blockIdx.x * 4 + wid) * 16;
  if (node0 + 16 > n) node0 = n - 16;              // overlap tail: duplicate identical writes
  u16* L = lt[wid];

  // A-frag: x[node0+q][8g..8g+7] -> bf16
  const float* xr = x + (node0 + q) * CC + 8 * g;
  float4 xa = *(const float4*)xr, xb = *(const float4*)(xr + 4);
  bf16x8 af;
  af[0] = (short)bf16r(xa.x); af[1] = (short)bf16r(xa.y);
  af[2] = (short)bf16r(xa.z); af[3] = (short)bf16r(xa.w);
  af[4] = (short)bf16r(xb.x); af[5] = (short)bf16r(xb.y);
  af[6] = (short)bf16r(xb.z); af[7] = (short)bf16r(xb.w);

#pragma unroll
  for (int nb = 0; nb < 16; ++nb) {
    bf16x8 bf = *(const bf16x8*)(Wb + nb * 512 + lane * 8);
    f32x4 acc = {0.f, 0.f, 0.f, 0.f};
    acc = __builtin_amdgcn_mfma_f32_16x16x32_bf16(af, bf, acc, 0, 0, 0);
    int col = 16 * nb + q;
#pragma unroll
    for (int r = 0; r < 4; ++r)
      L[(4 * g + r) * 264 + col] = (u16)bf16r(acc[r]);
  }
  __syncthreads();

  // a_src/a_dst: [16 nodes,256] x [256,16] via 8 chained mfma
  f32x4 az = {0.f, 0.f, 0.f, 0.f};
#pragma unroll
  for (int kb = 0; kb < 8; ++kb) {
    bf16x8 a2 = *(const bf16x8*)(L + q * 264 + kb * 32 + g * 8);
    bf16x8 zb = *(const bf16x8*)(Zb + kb * 512 + lane * 8);
    az = __builtin_amdgcn_mfma_f32_16x16x32_bf16(a2, zb, az, 0, 0, 0);
  }
  int hq = q & 7;
  u16* ascp16 = (u16*)ascp;
  if (q < 8) {                                     // a_src -> ascp lo16 (bf16)
#pragma unroll
    for (int r = 0; r < 4; ++r)
      ascp16[((node0 + 4 * g + r) * HH + hq) * 2] = (u16)bf16r(az[r]);
  } else {                                         // a_dst (fp32)
#pragma unroll
    for (int r = 0; r < 4; ++r)
      a_d[(node0 + 4 * g + r) * HH + hq] = az[r];
  }

  // per-(row,head) absmax -> fp16 scale (ascp hi16) + rinv (LDS)
#pragma unroll
  for (int t2 = 0; t2 < 2; ++t2) {
    int task = t2 * 64 + lane;                     // 128 tasks
    int r = task >> 3, h = task & 7;
    const unsigned* p = (const unsigned*)(L + r * 264 + h * 32);
    float mx = 0.f;
#pragma unroll
    for (int i = 0; i < 16; ++i) {
      unsigned w = p[i];
      mx = fmaxf(mx, fmaxf(fabsf(bflo(w)), fabsf(bfhi(w))));
    }
    float rinv = (mx > 0.f) ? 127.f / mx : 0.f;
    ascp16[((node0 + r) * HH + h) * 2 + 1] = f2h(mx * (1.f / 127.f));
    lsc[wid][r][h] = rinv;
  }
  __syncthreads();

  // int8 encode + store: 16 rows x 64 dwords, 16 dwords per lane
#pragma unroll
  for (int i = 0; i < 16; ++i) {
    int d = i * 64 + lane;
    int r = d >> 6, c = d & 63;                    // c: dword within 256B row
    int h = c >> 3;
    float rv = lsc[wid][r][h];
    const unsigned* p = (const unsigned*)(L + r * 264) + (c << 1);
    unsigned w0 = p[0], w1 = p[1];
    int q0 = __float2int_rn(bflo(w0) * rv);
    int q1 = __float2int_rn(bfhi(w0) * rv);
    int q2 = __float2int_rn(bflo(w1) * rv);
    int q3 = __float2int_rn(bfhi(w1) * rv);
    q0 = min(max(q0, -127), 127) + 128;
    q1 = min(max(q1, -127), 127) + 128;
    q2 = min(max(q2, -127), 127) + 128;
    q3 = min(max(q3, -127), 127) + 128;
    unsigned pk = (unsigned)q0 | ((unsigned)q1 << 8) |
                  ((unsigned)q2 << 16) | ((unsigned)q3 << 24);
    xq8[(node0 + r) * 64 + c] = pk;
  }
}

// ---------- scan phase A ----------
__global__ __launch_bounds__(256) void kscanA(const int* __restrict__ deg,
                                              int* __restrict__ bsum, int n)
{
  __shared__ int ws[4];
  int t = threadIdx.x;
  int i = (int)blockIdx.x * 1024 + t * 4;
  int4 v = make_int4(0, 0, 0, 0);
  if (i + 3 < n) v = *(const int4*)(deg + i);
  else {
    if (i     < n) v.x = deg[i];
    if (i + 1 < n) v.y = deg[i + 1];
    if (i + 2 < n) v.z = deg[i + 2];
    if (i + 3 < n) v.w = deg[i + 3];
  }
  int s = v.x + v.y + v.z + v.w;
#pragma unroll
  for (int mask = 1; mask < 64; mask <<= 1) s += __shfl_xor(s, mask);
  if ((t & 63) == 0) ws[t >> 6] = s;
  __syncthreads();
  if (t == 0) bsum[blockIdx.x] = ws[0] + ws[1] + ws[2] + ws[3];
}

// ---------- scan phase B ----------
__global__ __launch_bounds__(1024) void kscanB(int* __restrict__ bsum, int nb)
{
  __shared__ int wsum[16];
  int t = threadIdx.x, lane = t & 63, wid = t >> 6;
  int v = (t < nb) ? bsum[t] : 0;
  int s = v;
#pragma unroll
  for (int d = 1; d < 64; d <<= 1) { int tt = __shfl_up(s, d); if (lane >= d) s += tt; }
  if (lane == 63) wsum[wid] = s;
  __syncthreads();
  if (wid == 0) {
    int w = (lane < 16) ? wsum[lane] : 0;
#pragma unroll
    for (int d = 1; d < 16; d <<= 1) { int tt = __shfl_up(w, d); if (lane >= d) w += tt; }
    if (lane < 16) wsum[lane] = w;
  }
  __syncthreads();
  int excl = s - v + ((wid > 0) ? wsum[wid - 1] : 0);
  if (t < nb) bsum[t] = excl;
}

// ---------- scan phase C ----------
__global__ __launch_bounds__(256) void kscanC(const int* __restrict__ deg,
                                              const int* __restrict__ bsum,
                                              int* __restrict__ offs, int n)
{
  __shared__ int ws[4];
  int t = threadIdx.x, lane = t & 63, wid = t >> 6;
  int i = (int)blockIdx.x * 1024 + t * 4;
  int4 v = make_int4(0, 0, 0, 0);
  if (i + 3 < n) v = *(const int4*)(deg + i);
  else {
    if (i     < n) v.x = deg[i];
    if (i + 1 < n) v.y = deg[i + 1];
    if (i + 2 < n) v.z = deg[i + 2];
    if (i + 3 < n) v.w = deg[i + 3];
  }
  int tsum = v.x + v.y + v.z + v.w;
  int s = tsum;
#pragma unroll
  for (int d = 1; d < 64; d <<= 1) { int tt = __shfl_up(s, d); if (lane >= d) s += tt; }
  if (lane == 63) ws[wid] = s;
  __syncthreads();
  if (t == 0) {
    int a = ws[0]; ws[0] = 0;
    int b = ws[1]; ws[1] = a; a += b;
    int c = ws[2]; ws[2] = a; a += c;
    ws[3] = a;
  }
  __syncthreads();
  int base = bsum[blockIdx.x] + ws[wid] + (s - tsum);
  if (i     < n) offs[i]     = base; base += v.x;
  if (i + 1 < n) offs[i + 1] = base; base += v.y;
  if (i + 2 < n) offs[i + 2] = base; base += v.z;
  if (i + 3 < n) offs[i + 3] = base;
}

// ---------- CSR scatter: rank-based, ATOMIC-FREE, dst-quadrant L2-local writes ----------
__global__ __launch_bounds__(256) void kscatter(
    const int* __restrict__ ei, const unsigned* __restrict__ dstr, int e,
    const int* __restrict__ offs, int* __restrict__ csr, int n)
{
  int oct = (int)blockIdx.x & 3;
  int nsub = (int)gridDim.x >> 2;
  int sub = (int)blockIdx.x >> 2;
  int nper = (n + 3) >> 2;
  int lo = oct * nper, hi = lo + nper;
  int stride = nsub << 10;
  for (int i = (sub * 256 + (int)threadIdx.x) * 4; i < e; i += stride) {
    if (i + 3 < e) {
      uint4 d4 = *(const uint4*)(dstr + i);
      int4 s4 = *(const int4*)(ei + i);
      int dx = d4.x & 0x1ffff, dy = d4.y & 0x1ffff,
          dz = d4.z & 0x1ffff, dw = d4.w & 0x1ffff;
      if (dx >= lo && dx < hi) csr[offs[dx] + (d4.x >> 17)] = s4.x;
      if (dy >= lo && dy < hi) csr[offs[dy] + (d4.y >> 17)] = s4.y;
      if (dz >= lo && dz < hi) csr[offs[dz] + (d4.z >> 17)] = s4.z;
      if (dw >= lo && dw < hi) csr[offs[dw] + (d4.w >> 17)] = s4.w;
    } else {
      for (int k = 0; k < 4 && i + k < e; ++k) {
        unsigned dv = dstr[i + k];
        int d = dv & 0x1ffff;
        if (d >= lo && d < hi) csr[offs[d] + (dv >> 17)] = ei[i + k];
      }
    }
  }
}

// ---------- KAGG: wave-per-4-nodes, chunk-of-8, fixed-reference softmax + int8 gather ----------
// defer-max: p = exp(alpha - aself) (bounded, validated round 10). No online max/rescale.
// A-layout: eg=lane>>3 (edge in chunk), ha=lane&7 (head) — stage p, pw per edge.
// B-layout: hb=lane>>3 (head), (lane&7) dword — gather + fma.
// dn/osum accumulate per-lane in A-layout, ONE butterfly reduce per node at the end.
__global__ __launch_bounds__(256) void kagg(
    const int* __restrict__ csr, const int* __restrict__ offs,
    const int* __restrict__ deg,
    const unsigned* __restrict__ ascp, const float* __restrict__ a_d,
    const unsigned* __restrict__ xq8, float* __restrict__ og, int n)
{
  int lane = threadIdx.x & 63;
  int wid  = threadIdx.x >> 6;
  int base = ((int)blockIdx.x * 4 + wid) * 4;      // 4 nodes per wave
  int eg = lane >> 3, ha = lane & 7;
  int hb = eg;
  int doff = hb * 8 + (lane & 7);

  for (int t = 0; t < 4; ++t) {
    int node = base + t;
    if (node >= n) return;
    int start = offs[node];
    int dg = deg[node];
    unsigned aw_self = ascp[(size_t)node * HH + ha];
    float ad_a  = a_d[(size_t)node * HH + ha];
    float aself = leaky(bflo(aw_self) + ad_a);

    float acc0 = 0.f, acc1 = 0.f, acc2 = 0.f, acc3 = 0.f;
    float dnA = 0.f, osA = 0.f;

    for (int j0 = 0; j0 < dg; j0 += 8) {
      int cnt = dg - j0; if (cnt > 8) cnt = 8;
      int idx = j0 + eg;
      int srcl = 0; float pw = 0.f;
      if (idx < dg) {
        srcl = csr[start + idx];
        unsigned av = ascp[(size_t)srcl * HH + ha];
        float al = leaky(bflo(av) + ad_a);
        float p  = __expf(al - aself);
        pw = p * h2f(av >> 16);
        dnA += p; osA += pw;
      }
      if (cnt == 8) {
#pragma unroll
        for (int j = 0; j < 8; ++j) {
          float wt = __shfl(pw, (j << 3) + hb);
          int s = __shfl(srcl, j << 3);
          unsigned w = xq8[(size_t)s * 64 + doff];
          acc0 = fmaf(ub0(w), wt, acc0);
          acc1 = fmaf(ub1(w), wt, acc1);
          acc2 = fmaf(ub2(w), wt, acc2);
          acc3 = fmaf(ub3(w), wt, acc3);
        }
      } else {
        for (int j = 0; j < cnt; ++j) {
          float wt = __shfl(pw, (j << 3) + hb);
          int s = __shfl(srcl, j << 3);
          unsigned w = xq8[(size_t)s * 64 + doff];
          acc0 = fmaf(ub0(w), wt, acc0);
          acc1 = fmaf(ub1(w), wt, acc1);
          acc2 = fmaf(ub2(w), wt, acc2);
          acc3 = fmaf(ub3(w), wt, acc3);
        }
      }
    }

    // reduce dn/osum over edge-slot dim (eg): after this, value is per-head ha
    float dnH = dnA, osH = osA;
    dnH += __shfl_xor(dnH, 8);  osH += __shfl_xor(osH, 8);
    dnH += __shfl_xor(dnH, 16); osH += __shfl_xor(osH, 16);
    dnH += __shfl_xor(dnH, 32); osH += __shfl_xor(osH, 32);
    // B-layout views for head hb (lane hb holds head hb: hb<8 -> ha==hb)
    float dnB = __shfl(dnH, hb);
    float osB = __shfl(osH, hb);
    float scB = __shfl(h2f(aw_self >> 16), hb);

    // self loop: p = 1
    {
      unsigned w = xq8[(size_t)node * 64 + doff];
      dnB += 1.f; osB += scB;
      acc0 = fmaf(ub0(w), scB, acc0);
      acc1 = fmaf(ub1(w), scB, acc1);
      acc2 = fmaf(ub2(w), scB, acc2);
      acc3 = fmaf(ub3(w), scB, acc3);
    }

    float corr = -128.f * osB;
    float inv = 0.125f / dnB;
    acc0 = (acc0 + corr) * inv;
    acc1 = (acc1 + corr) * inv;
    acc2 = (acc2 + corr) * inv;
    acc3 = (acc3 + corr) * inv;
#pragma unroll
    for (int mask = 8; mask < 64; mask <<= 1) {
      acc0 += __shfl_xor(acc0, mask);
      acc1 += __shfl_xor(acc1, mask);
      acc2 += __shfl_xor(acc2, mask);
      acc3 += __shfl_xor(acc3, mask);
    }
    if (lane < 8) {
      *(float4*)(og + (size_t)node * CC + lane * 4) =
        make_float4(acc0, acc1, acc2, acc3);
    }
  }
}

// ---------- K5M: MFMA tail — LN1 + FFN(mfma) + LN2 ----------
__global__ __launch_bounds__(256) void k5m(
    const float* __restrict__ og, const float* __restrict__ x,
    const float* __restrict__ bg,
    const u16* __restrict__ V1b, const u16* __restrict__ V2b,
    const float* __restrict__ b1, const float* __restrict__ b2,
    const float* __restrict__ g1, const float* __restrict__ be1,
    const float* __restrict__ g2, const float* __restrict__ be2,
    float* __restrict__ out, int n)
{
  __shared__ u16   lh[4][16 * 40];
  __shared__ u16   lf[4][16 * 136];
  __shared__ float lo[4][16 * 36];
  int wid = threadIdx.x >> 6, lane = threadIdx.x & 63;
  int q = lane & 15, g = lane >> 4;
  long node0 = (long)((int)blockIdx.x * 4 + wid) * 16;
  if (node0 + 16 > n) node0 = n - 16;
  u16* LH = lh[wid]; u16* LF = lf[wid]; float* LO = lo[wid];

  {
    int row = lane >> 2, off = (lane & 3) * 8;
    const float* o8 = og + (node0 + row) * CC + off;
    const float* x8 = x  + (node0 + row) * CC + off;
    float4 a0 = *(const float4*)o8, a1 = *(const float4*)(o8 + 4);
    float4 c0 = *(const float4*)x8, c1 = *(const float4*)(x8 + 4);
    float4 bg0 = *(const float4*)(bg + off), bg1 = *(const float4*)(bg + off + 4);
    float4 s0 = make_float4(a0.x + c0.x + bg0.x, a0.y + c0.y + bg0.y,
                            a0.z + c0.z + bg0.z, a0.w + c0.w + bg0.w);
    float4 s1 = make_float4(a1.x + c1.x + bg1.x, a1.y + c1.y + bg1.y,
                            a1.z + c1.z + bg1.z, a1.w + c1.w + bg1.w);
    *(float4*)(LO + row * 36 + off)     = s0;
    *(float4*)(LO + row * 36 + off + 4) = s1;
  }
  __syncthreads();

  float hv[32];
  if (lane < 16) {
#pragma unroll
    for (int i = 0; i < 8; ++i) {
      float4 t = *(const float4*)(LO + q * 36 + i * 4);
      hv[4*i] = t.x; hv[4*i+1] = t.y; hv[4*i+2] = t.z; hv[4*i+3] = t.w;
    }
    float mu = 0.f;
#pragma unroll
    for (int c = 0; c < 32; ++c) mu += hv[c];
    mu *= (1.f / 32.f);
    float var = 0.f;
#pragma unroll
    for (int c = 0; c < 32; ++c) { float t = hv[c] - mu; var = fmaf(t, t, var); }
    float rs = rsqrtf(var * (1.f / 32.f) + LNEPS);
#pragma unroll
    for (int c = 0; c < 32; ++c) hv[c] = (hv[c] - mu) * rs * g1[c] + be1[c];
    uint* dst = (uint*)(LH + q * 40);
#pragma unroll
    for (int i = 0; i < 16; ++i)
      dst[i] = bf16r(hv[2*i]) | (bf16r(hv[2*i+1]) << 16);
  }
  __syncthreads();

  bf16x8 ah = *(const bf16x8*)(LH + q * 40 + g * 8);
#pragma unroll
  for (int nb = 0; nb < 8; ++nb) {
    bf16x8 v1 = *(const bf16x8*)(V1b + nb * 512 + lane * 8);
    f32x4 acc = {0.f, 0.f, 0.f, 0.f};
    acc = __builtin_amdgcn_mfma_f32_16x16x32_bf16(ah, v1, acc, 0, 0, 0);
    int col = 16 * nb + q;
    float bias = b1[col];
#pragma unroll
    for (int r = 0; r < 4; ++r) {
      float f = fmaxf(acc[r] + bias, 0.f);
      LF[(4 * g + r) * 136 + col] = (u16)bf16r(f);
    }
  }
  __syncthreads();

  f32x4 a20 = {0.f, 0.f, 0.f, 0.f}, a21 = {0.f, 0.f, 0.f, 0.f};
#pragma unroll
  for (int kb = 0; kb < 4; ++kb) {
    bf16x8 af2 = *(const bf16x8*)(LF + q * 136 + kb * 32 + g * 8);
    bf16x8 v20 = *(const bf16x8*)(V2b + (kb * 2 + 0) * 512 + lane * 8);
    bf16x8 v21 = *(const bf16x8*)(V2b + (kb * 2 + 1) * 512 + lane * 8);
    a20 = __builtin_amdgcn_mfma_f32_16x16x32_bf16(af2, v20, a20, 0, 0, 0);
    a21 = __builtin_amdgcn_mfma_f32_16x16x32_bf16(af2, v21, a21, 0, 0, 0);
  }
  __syncthreads();
#pragma unroll
  for (int r = 0; r < 4; ++r) {
    LO[(4 * g + r) * 36 + q]      = a20[r];
    LO[(4 * g + r) * 36 + 16 + q] = a21[r];
  }
  __syncthreads();

  if (lane < 16) {
    float ov[32];
#pragma unroll
    for (int i = 0; i < 8; ++i) {
      float4 t = *(const float4*)(LO + q * 36 + i * 4);
      ov[4*i] = t.x; ov[4*i+1] = t.y; ov[4*i+2] = t.z; ov[4*i+3] = t.w;
    }
#pragma unroll
    for (int c = 0; c < 32; ++c) ov[c] += b2[c] + hv[c];
    float mu2 = 0.f;
#pragma unroll
    for (int c = 0; c < 32; ++c) mu2 += ov[c];
    mu2 *= (1.f / 32.f);
    float var2 = 0.f;
#pragma unroll
    for (int c = 0; c < 32; ++c) { float t = ov[c] - mu2; var2 = fmaf(t, t, var2); }
    float rs2 = rsqrtf(var2 * (1.f / 32.f) + LNEPS);
    float* op = out + (node0 + q) * CC;
#pragma unroll
    for (int i = 0; i < 8; ++i) {
      float4 o;
      o.x = (ov[4*i]   - mu2) * rs2 * g2[4*i]   + be2[4*i];
      o.y = (ov[4*i+1] - mu2) * rs2 * g2[4*i+1] + be2[4*i+1];
      o.z = (ov[4*i+2] - mu2) * rs2 * g2[4*i+2] + be2[4*i+2];
      o.w = (ov[4*i+3] - mu2) * rs2 * g2[4*i+3] + be2[4*i+3];
      *(float4*)(op + i * 4) = o;
    }
  }
}

// ---------- launch ----------
extern "C" void kernel_launch(void* const* d_in, const int* in_sizes, int n_in,
                              void* d_out, int out_size, void* d_ws, size_t ws_size,
                              hipStream_t stream)
{
  const float* x    = (const float*)d_in[0];
  const int*   ei   = (const int*)d_in[1];
  const float* W    = (const float*)d_in[2];
  const float* atts = (const float*)d_in[3];
  const float* attd = (const float*)d_in[4];
  const float* bg   = (const float*)d_in[5];
  const float* w1   = (const float*)d_in[6];
  const float* b1   = (const float*)d_in[7];
  const float* w2   = (const float*)d_in[8];
  const float* b2   = (const float*)d_in[9];
  const float* g1   = (const float*)d_in[10];
  const float* be1  = (const float*)d_in[11];
  const float* g2   = (const float*)d_in[12];
  const float* be2  = (const float*)d_in[13];

  int n = in_sizes[0] / CC;
  int e = in_sizes[1] / 2;

  uint8_t* ws = (uint8_t*)d_ws;
  size_t o = 0;
  unsigned* xq8 = (unsigned*)(ws + o); o += (size_t)n * 256;   // int8 rows, 256B/node
  unsigned* ascp = (unsigned*)(ws + o); o += (size_t)n * HH * 4; // bf16 a_src|fp16 scale
  float* a_d = (float*)(ws + o); o += (size_t)n * HH * 4;
  float* og  = (float*)(ws + o); o += (size_t)n * CC * 4;
  int* deg    = (int*)(ws + o); o += (size_t)n * 4;
  int* offs   = (int*)(ws + o); o += (size_t)n * 4;
  unsigned* dstr = (unsigned*)(ws + o); o += (size_t)e * 4;
  int* csr    = (int*)(ws + o); o += (size_t)e * 4;
  int* bsum   = (int*)(ws + o); o += 4096;
  u16* Wb  = (u16*)(ws + o); o += 16 * 512 * 2;
  u16* Zb  = (u16*)(ws + o); o += 8 * 512 * 2;
  u16* V1b = (u16*)(ws + o); o += 8 * 512 * 2;
  u16* V2b = (u16*)(ws + o); o += 8 * 512 * 2;

  (void)hipMemsetAsync(deg, 0, (size_t)n * 4, stream);

  int nwaves = (n + 15) / 16;
  int nbc   = (nwaves + 3) / 4;
  int nb_e4 = (e + 1023) / 1024;
  int nb_s  = (n + 1023) / 1024;
  int nb_ag = (n + 15) / 16;        // 4 waves x 4 nodes = 16 nodes per block

  klayout <<<1, 256, 0, stream>>>(W, atts, attd, w1, w2, Wb, Zb, V1b, V2b);
  k1m     <<<nbc + nb_e4, 256, 0, stream>>>(x, Wb, Zb, ei, xq8, ascp, a_d, deg,
                                            dstr, n, e, nbc);
  kscanA  <<<nb_s, 256, 0, stream>>>(deg, bsum, n);
  kscanB  <<<1, 1024, 0, stream>>>(bsum, nb_s);
  kscanC  <<<nb_s, 256, 0, stream>>>(deg, bsum, offs, n);
  kscatter<<<512, 256, 0, stream>>>(ei, dstr, e, offs, csr, n);
  kagg    <<<nb_ag, 256, 0, stream>>>(csr, offs, deg, ascp, a_d, xq8, og, n);
  k5m     <<<nbc, 256, 0, stream>>>(og, x, bg, V1b, V2b, b1, b2, g1, be1, g2, be2,
                                    (float*)d_out, n);
}

// Round 13
// 253.277 us; speedup vs baseline: 1.2970x; 1.0365x over previous
//
#include <hip/hip_runtime.h>
#include <hip/hip_fp16.h>
#include <stdint.h>

#define HH 8
#define CC 32
#define HC 256   // H*C
#define FF 128
#define NEG 0.2f
#define LNEPS 1e-5f

typedef __attribute__((ext_vector_type(8))) short bf16x8;
typedef __attribute__((ext_vector_type(4))) float f32x4;
typedef unsigned short u16;

// ---------- helpers ----------
__device__ inline unsigned bf16r(float f) {           // round-to-nearest-even bf16
  unsigned u = __float_as_uint(f);
  return (u + 0x7fffu + ((u >> 16) & 1u)) >> 16;
}
__device__ inline float bflo(unsigned w) { return __uint_as_float(w << 16); }
__device__ inline float bfhi(unsigned w) { return __uint_as_float(w & 0xffff0000u); }
__device__ inline float leaky(float v) { return v >= 0.f ? v : NEG * v; }
__device__ inline float h2f(unsigned hbits) {
  return __half2float(__ushort_as_half((unsigned short)hbits));
}
__device__ inline u16 f2h(float f) {
  return __half_as_ushort(__float2half(f));
}
// byte extract -> float (v_cvt_f32_ubyte0..3)
__device__ inline float ub0(unsigned w) { return (float)(w & 0xffu); }
__device__ inline float ub1(unsigned w) { return (float)((w >> 8) & 0xffu); }
__device__ inline float ub2(unsigned w) { return (float)((w >> 16) & 0xffu); }
__device__ inline float ub3(unsigned w) { return (float)(w >> 24); }

// ---------- KLAYOUT: repack weights into MFMA B-fragment layout (bf16) ----------
__global__ __launch_bounds__(256) void klayout(
    const float* __restrict__ W, const float* __restrict__ atts,
    const float* __restrict__ attd, const float* __restrict__ w1,
    const float* __restrict__ w2,
    u16* __restrict__ Wb, u16* __restrict__ Zb,
    u16* __restrict__ V1b, u16* __restrict__ V2b)
{
  int t = threadIdx.x;
  for (int i = t; i < 16 * 512; i += 256) {        // Wb: W_gat [32,256]
    int j = i & 7, l = (i >> 3) & 63, nb = i >> 9;
    int k = 8 * (l >> 4) + j, c = 16 * nb + (l & 15);
    Wb[i] = (u16)bf16r(W[k * HC + c]);
  }
  for (int i = t; i < 8 * 512; i += 256) {         // Zb: [256,16] = [atts|attd] blockdiag
    int j = i & 7, l = (i >> 3) & 63, kb = i >> 9;
    int k = 32 * kb + 8 * (l >> 4) + j;
    int tc = l & 15;
    float v = 0.f;
    if (tc < 8)  { if ((k >> 5) == tc)     v = atts[tc * 32 + (k & 31)]; }
    else         { if ((k >> 5) == tc - 8) v = attd[(tc - 8) * 32 + (k & 31)]; }
    Zb[i] = (u16)bf16r(v);
  }
  for (int i = t; i < 8 * 512; i += 256) {         // V1b: w1 [32,128]
    int j = i & 7, l = (i >> 3) & 63, nb = i >> 9;
    int k = 8 * (l >> 4) + j, c = 16 * nb + (l & 15);
    V1b[i] = (u16)bf16r(w1[k * FF + c]);
  }
  for (int i = t; i < 8 * 512; i += 256) {         // V2b: w2 [128,32]
    int j = i & 7, l = (i >> 3) & 63, kn = i >> 9;
    int kb = kn >> 1, nb2 = kn & 1;
    int k = 32 * kb + 8 * (l >> 4) + j, c = 16 * nb2 + (l & 15);
    V2b[i] = (u16)bf16r(w2[k * CC + c]);
  }
}

// ---------- KHIST: replicated-counter histogram + (replica, rank) emit ----------
// deg4[r][d], replica r = blockIdx&3 -> 4x less per-line contention on the
// memory-side atomic RMWs. dstr = d | r<<17 | rank<<19.
__global__ __launch_bounds__(256) void khist(
    const int* __restrict__ ei, int e, int n,
    int* __restrict__ deg4, unsigned* __restrict__ dstr)
{
  int r = (int)blockIdx.x & 3;
  int* dr = deg4 + (size_t)r * n;
  int i = (int)blockIdx.x * 1024 + (int)threadIdx.x * 4;
  if (i >= e) return;
  const int* dst = ei + e;
  if (i + 3 < e) {
    int4 d4 = *(const int4*)(dst + i);
    unsigned r0 = (unsigned)atomicAdd(&dr[d4.x], 1);
    unsigned r1 = (unsigned)atomicAdd(&dr[d4.y], 1);
    unsigned r2 = (unsigned)atomicAdd(&dr[d4.z], 1);
    unsigned r3 = (unsigned)atomicAdd(&dr[d4.w], 1);
    uint4 o;
    o.x = (unsigned)d4.x | ((unsigned)r << 17) | (r0 << 19);
    o.y = (unsigned)d4.y | ((unsigned)r << 17) | (r1 << 19);
    o.z = (unsigned)d4.z | ((unsigned)r << 17) | (r2 << 19);
    o.w = (unsigned)d4.w | ((unsigned)r << 17) | (r3 << 19);
    *(uint4*)(dstr + i) = o;
  } else {
    for (int k = 0; k < 4 && i + k < e; ++k) {
      int d = dst[i + k];
      unsigned rr = (unsigned)atomicAdd(&dr[d], 1);
      dstr[i + k] = (unsigned)d | ((unsigned)r << 17) | (rr << 19);
    }
  }
}

// ---------- K1C: MFMA xp=x@W -> int8 rows + packed (bf16 a_src|fp16 scale) + a_dst ----------
__global__ __launch_bounds__(256) void k1c(
    const float* __restrict__ x, const u16* __restrict__ Wb,
    const u16* __restrict__ Zb,
    unsigned* __restrict__ xq8, unsigned* __restrict__ ascp,
    float* __restrict__ a_d, int n)
{
  __shared__ u16 lt[4][16 * 264];                  // per-wave [16 rows][264 halfs]
  __shared__ float lsc[4][16][8];                  // per-wave rinv = 127/rowmax
  int wid = threadIdx.x >> 6, lane = threadIdx.x & 63;
  int q = lane & 15, g = lane >> 4;
  long node0 = (long)((int)blockIdx.x * 4 + wid) * 16;
  if (node0 + 16 > n) node0 = n - 16;              // overlap tail: duplicate identical writes
  u16* L = lt[wid];

  // A-frag: x[node0+q][8g..8g+7] -> bf16
  const float* xr = x + (node0 + q) * CC + 8 * g;
  float4 xa = *(const float4*)xr, xb = *(const float4*)(xr + 4);
  bf16x8 af;
  af[0] = (short)bf16r(xa.x); af[1] = (short)bf16r(xa.y);
  af[2] = (short)bf16r(xa.z); af[3] = (short)bf16r(xa.w);
  af[4] = (short)bf16r(xb.x); af[5] = (short)bf16r(xb.y);
  af[6] = (short)bf16r(xb.z); af[7] = (short)bf16r(xb.w);

#pragma unroll
  for (int nb = 0; nb < 16; ++nb) {
    bf16x8 bf = *(const bf16x8*)(Wb + nb * 512 + lane * 8);
    f32x4 acc = {0.f, 0.f, 0.f, 0.f};
    acc = __builtin_amdgcn_mfma_f32_16x16x32_bf16(af, bf, acc, 0, 0, 0);
    int col = 16 * nb + q;
#pragma unroll
    for (int r = 0; r < 4; ++r)
      L[(4 * g + r) * 264 + col] = (u16)bf16r(acc[r]);
  }
  __syncthreads();

  // a_src/a_dst: [16 nodes,256] x [256,16] via 8 chained mfma
  f32x4 az = {0.f, 0.f, 0.f, 0.f};
#pragma unroll
  for (int kb = 0; kb < 8; ++kb) {
    bf16x8 a2 = *(const bf16x8*)(L + q * 264 + kb * 32 + g * 8);
    bf16x8 zb = *(const bf16x8*)(Zb + kb * 512 + lane * 8);
    az = __builtin_amdgcn_mfma_f32_16x16x32_bf16(a2, zb, az, 0, 0, 0);
  }
  int hq = q & 7;
  u16* ascp16 = (u16*)ascp;
  if (q < 8) {                                     // a_src -> ascp lo16 (bf16)
#pragma unroll
    for (int r = 0; r < 4; ++r)
      ascp16[((node0 + 4 * g + r) * HH + hq) * 2] = (u16)bf16r(az[r]);
  } else {                                         // a_dst (fp32)
#pragma unroll
    for (int r = 0; r < 4; ++r)
      a_d[(node0 + 4 * g + r) * HH + hq] = az[r];
  }

  // per-(row,head) absmax -> fp16 scale (ascp hi16) + rinv (LDS)
#pragma unroll
  for (int t2 = 0; t2 < 2; ++t2) {
    int task = t2 * 64 + lane;                     // 128 tasks
    int r = task >> 3, h = task & 7;
    const unsigned* p = (const unsigned*)(L + r * 264 + h * 32);
    float mx = 0.f;
#pragma unroll
    for (int i = 0; i < 16; ++i) {
      unsigned w = p[i];
      mx = fmaxf(mx, fmaxf(fabsf(bflo(w)), fabsf(bfhi(w))));
    }
    float rinv = (mx > 0.f) ? 127.f / mx : 0.f;
    ascp16[((node0 + r) * HH + h) * 2 + 1] = f2h(mx * (1.f / 127.f));
    lsc[wid][r][h] = rinv;
  }
  __syncthreads();

  // int8 encode + store: 16 rows x 64 dwords, 16 dwords per lane
#pragma unroll
  for (int i = 0; i < 16; ++i) {
    int d = i * 64 + lane;
    int r = d >> 6, c = d & 63;                    // c: dword within 256B row
    int h = c >> 3;
    float rv = lsc[wid][r][h];
    const unsigned* p = (const unsigned*)(L + r * 264) + (c << 1);
    unsigned w0 = p[0], w1 = p[1];
    int q0 = __float2int_rn(bflo(w0) * rv);
    int q1 = __float2int_rn(bfhi(w0) * rv);
    int q2 = __float2int_rn(bflo(w1) * rv);
    int q3 = __float2int_rn(bfhi(w1) * rv);
    q0 = min(max(q0, -127), 127) + 128;
    q1 = min(max(q1, -127), 127) + 128;
    q2 = min(max(q2, -127), 127) + 128;
    q3 = min(max(q3, -127), 127) + 128;
    unsigned pk = (unsigned)q0 | ((unsigned)q1 << 8) |
                  ((unsigned)q2 << 16) | ((unsigned)q3 << 24);
    xq8[(node0 + r) * 64 + c] = pk;
  }
}

// ---------- scan phase A: per-1024-block sums (over 4 replicas) ----------
__global__ __launch_bounds__(256) void kscanA(const int* __restrict__ deg4,
                                              int* __restrict__ bsum, int n)
{
  __shared__ int ws[4];
  int t = threadIdx.x;
  int i = (int)blockIdx.x * 1024 + t * 4;
  int s = 0;
  if (i + 3 < n) {
#pragma unroll
    for (int r = 0; r < 4; ++r) {
      int4 v = *(const int4*)(deg4 + (size_t)r * n + i);
      s += v.x + v.y + v.z + v.w;
    }
  } else {
    for (int k = 0; k < 4 && i + k < n; ++k)
#pragma unroll
      for (int r = 0; r < 4; ++r) s += deg4[(size_t)r * n + i + k];
  }
#pragma unroll
  for (int mask = 1; mask < 64; mask <<= 1) s += __shfl_xor(s, mask);
  if ((t & 63) == 0) ws[t >> 6] = s;
  __syncthreads();
  if (t == 0) bsum[blockIdx.x] = ws[0] + ws[1] + ws[2] + ws[3];
}

// ---------- scan phase B ----------
__global__ __launch_bounds__(1024) void kscanB(int* __restrict__ bsum, int nb)
{
  __shared__ int wsum[16];
  int t = threadIdx.x, lane = t & 63, wid = t >> 6;
  int v = (t < nb) ? bsum[t] : 0;
  int s = v;
#pragma unroll
  for (int d = 1; d < 64; d <<= 1) { int tt = __shfl_up(s, d); if (lane >= d) s += tt; }
  if (lane == 63) wsum[wid] = s;
  __syncthreads();
  if (wid == 0) {
    int w = (lane < 16) ? wsum[lane] : 0;
#pragma unroll
    for (int d = 1; d < 16; d <<= 1) { int tt = __shfl_up(w, d); if (lane >= d) w += tt; }
    if (lane < 16) wsum[lane] = w;
  }
  __syncthreads();
  int excl = s - v + ((wid > 0) ? wsum[wid - 1] : 0);
  if (t < nb) bsum[t] = excl;
}

// ---------- scan phase C: offs (=rb[0]) + per-replica bases rb[1..3] + degt ----------
__global__ __launch_bounds__(256) void kscanC(const int* __restrict__ deg4,
                                              const int* __restrict__ bsum,
                                              int* __restrict__ rb,
                                              int* __restrict__ degt, int n)
{
  __shared__ int ws[4];
  int t = threadIdx.x, lane = t & 63, wid = t >> 6;
  int i = (int)blockIdx.x * 1024 + t * 4;
  int c0[4] = {0,0,0,0}, c1[4] = {0,0,0,0}, c2[4] = {0,0,0,0}, c3[4] = {0,0,0,0};
  if (i + 3 < n) {
    int4 v0 = *(const int4*)(deg4 + 0 * (size_t)n + i);
    int4 v1 = *(const int4*)(deg4 + 1 * (size_t)n + i);
    int4 v2 = *(const int4*)(deg4 + 2 * (size_t)n + i);
    int4 v3 = *(const int4*)(deg4 + 3 * (size_t)n + i);
    c0[0]=v0.x;c0[1]=v0.y;c0[2]=v0.z;c0[3]=v0.w;
    c1[0]=v1.x;c1[1]=v1.y;c1[2]=v1.z;c1[3]=v1.w;
    c2[0]=v2.x;c2[1]=v2.y;c2[2]=v2.z;c2[3]=v2.w;
    c3[0]=v3.x;c3[1]=v3.y;c3[2]=v3.z;c3[3]=v3.w;
  } else {
    for (int k = 0; k < 4 && i + k < n; ++k) {
      c0[k] = deg4[0 * (size_t)n + i + k];
      c1[k] = deg4[1 * (size_t)n + i + k];
      c2[k] = deg4[2 * (size_t)n + i + k];
      c3[k] = deg4[3 * (size_t)n + i + k];
    }
  }
  int tot[4];
#pragma unroll
  for (int k = 0; k < 4; ++k) tot[k] = c0[k] + c1[k] + c2[k] + c3[k];
  int tsum = tot[0] + tot[1] + tot[2] + tot[3];
  int s = tsum;
#pragma unroll
  for (int d = 1; d < 64; d <<= 1) { int tt = __shfl_up(s, d); if (lane >= d) s += tt; }
  if (lane == 63) ws[wid] = s;
  __syncthreads();
  if (t == 0) {
    int a = ws[0]; ws[0] = 0;
    int b = ws[1]; ws[1] = a; a += b;
    int c = ws[2]; ws[2] = a; a += c;
    ws[3] = a;
  }
  __syncthreads();
  int base = bsum[blockIdx.x] + ws[wid] + (s - tsum);
#pragma unroll
  for (int k = 0; k < 4; ++k) {
    if (i + k < n) {
      int b0 = base;
      rb[0 * (size_t)n + i + k] = b0;
      rb[1 * (size_t)n + i + k] = b0 + c0[k];
      rb[2 * (size_t)n + i + k] = b0 + c0[k] + c1[k];
      rb[3 * (size_t)n + i + k] = b0 + c0[k] + c1[k] + c2[k];
      degt[i + k] = tot[k];
    }
    base += tot[k];
  }
}

// ---------- CSR scatter: rank-based, ATOMIC-FREE, dst-quadrant L2-local writes ----------
__global__ __launch_bounds__(256) void kscatter(
    const int* __restrict__ ei, const unsigned* __restrict__ dstr, int e,
    const int* __restrict__ rb, int* __restrict__ csr, int n)
{
  int oct = (int)blockIdx.x & 3;
  int nsub = (int)gridDim.x >> 2;
  int sub = (int)blockIdx.x >> 2;
  int nper = (n + 3) >> 2;
  int lo = oct * nper, hi = lo + nper;
  int stride = nsub << 10;
  for (int i = (sub * 256 + (int)threadIdx.x) * 4; i < e; i += stride) {
    if (i + 3 < e) {
      uint4 d4 = *(const uint4*)(dstr + i);
      int4 s4 = *(const int4*)(ei + i);
      int dx = d4.x & 0x1ffff, dy = d4.y & 0x1ffff,
          dz = d4.z & 0x1ffff, dw = d4.w & 0x1ffff;
      if (dx >= lo && dx < hi)
        csr[rb[(size_t)((d4.x >> 17) & 3) * n + dx] + (d4.x >> 19)] = s4.x;
      if (dy >= lo && dy < hi)
        csr[rb[(size_t)((d4.y >> 17) & 3) * n + dy] + (d4.y >> 19)] = s4.y;
      if (dz >= lo && dz < hi)
        csr[rb[(size_t)((d4.z >> 17) & 3) * n + dz] + (d4.z >> 19)] = s4.z;
      if (dw >= lo && dw < hi)
        csr[rb[(size_t)((d4.w >> 17) & 3) * n + dw] + (d4.w >> 19)] = s4.w;
    } else {
      for (int k = 0; k < 4 && i + k < e; ++k) {
        unsigned dv = dstr[i + k];
        int d = dv & 0x1ffff;
        if (d >= lo && d < hi)
          csr[rb[(size_t)((dv >> 17) & 3) * n + d] + (dv >> 19)] = ei[i + k];
      }
    }
  }
}

// ---------- KAGG: wave-per-4-nodes, chunk-of-8, fixed-reference softmax + int8 gather ----------
__global__ __launch_bounds__(256) void kagg(
    const int* __restrict__ csr, const int* __restrict__ offs,
    const int* __restrict__ degt,
    const unsigned* __restrict__ ascp, const float* __restrict__ a_d,
    const unsigned* __restrict__ xq8, float* __restrict__ og, int n)
{
  int lane = threadIdx.x & 63;
  int wid  = threadIdx.x >> 6;
  int base = ((int)blockIdx.x * 4 + wid) * 4;      // 4 nodes per wave
  int eg = lane >> 3, ha = lane & 7;
  int hb = eg;
  int doff = hb * 8 + (lane & 7);

  for (int t = 0; t < 4; ++t) {
    int node = base + t;
    if (node >= n) return;
    int start = offs[node];
    int dg = degt[node];
    unsigned aw_self = ascp[(size_t)node * HH + ha];
    float ad_a  = a_d[(size_t)node * HH + ha];
    float aself = leaky(bflo(aw_self) + ad_a);

    float acc0 = 0.f, acc1 = 0.f, acc2 = 0.f, acc3 = 0.f;
    float dnA = 0.f, osA = 0.f;

    for (int j0 = 0; j0 < dg; j0 += 8) {
      int cnt = dg - j0; if (cnt > 8) cnt = 8;
      int idx = j0 + eg;
      int srcl = 0; float pw = 0.f;
      if (idx < dg) {
        srcl = csr[start + idx];
        unsigned av = ascp[(size_t)srcl * HH + ha];
        float al = leaky(bflo(av) + ad_a);
        float p  = __expf(al - aself);
        pw = p * h2f(av >> 16);
        dnA += p; osA += pw;
      }
      if (cnt == 8) {
#pragma unroll
        for (int j = 0; j < 8; ++j) {
          float wt = __shfl(pw, (j << 3) + hb);
          int s = __shfl(srcl, j << 3);
          unsigned w = xq8[(size_t)s * 64 + doff];
          acc0 = fmaf(ub0(w), wt, acc0);
          acc1 = fmaf(ub1(w), wt, acc1);
          acc2 = fmaf(ub2(w), wt, acc2);
          acc3 = fmaf(ub3(w), wt, acc3);
        }
      } else {
        for (int j = 0; j < cnt; ++j) {
          float wt = __shfl(pw, (j << 3) + hb);
          int s = __shfl(srcl, j << 3);
          unsigned w = xq8[(size_t)s * 64 + doff];
          acc0 = fmaf(ub0(w), wt, acc0);
          acc1 = fmaf(ub1(w), wt, acc1);
          acc2 = fmaf(ub2(w), wt, acc2);
          acc3 = fmaf(ub3(w), wt, acc3);
        }
      }
    }

    // reduce dn/osum over edge-slot dim (eg): after this, value is per-head ha
    float dnH = dnA, osH = osA;
    dnH += __shfl_xor(dnH, 8);  osH += __shfl_xor(osH, 8);
    dnH += __shfl_xor(dnH, 16); osH += __shfl_xor(osH, 16);
    dnH += __shfl_xor(dnH, 32); osH += __shfl_xor(osH, 32);
    float dnB = __shfl(dnH, hb);
    float osB = __shfl(osH, hb);
    float scB = __shfl(h2f(aw_self >> 16), hb);

    // self loop: p = 1
    {
      unsigned w = xq8[(size_t)node * 64 + doff];
      dnB += 1.f; osB += scB;
      acc0 = fmaf(ub0(w), scB, acc0);
      acc1 = fmaf(ub1(w), scB, acc1);
      acc2 = fmaf(ub2(w), scB, acc2);
      acc3 = fmaf(ub3(w), scB, acc3);
    }

    float corr = -128.f * osB;
    float inv = 0.125f / dnB;
    acc0 = (acc0 + corr) * inv;
    acc1 = (acc1 + corr) * inv;
    acc2 = (acc2 + corr) * inv;
    acc3 = (acc3 + corr) * inv;
#pragma unroll
    for (int mask = 8; mask < 64; mask <<= 1) {
      acc0 += __shfl_xor(acc0, mask);
      acc1 += __shfl_xor(acc1, mask);
      acc2 += __shfl_xor(acc2, mask);
      acc3 += __shfl_xor(acc3, mask);
    }
    if (lane < 8) {
      *(float4*)(og + (size_t)node * CC + lane * 4) =
        make_float4(acc0, acc1, acc2, acc3);
    }
  }
}

// ---------- K5M: MFMA tail — LN1 + FFN(mfma) + LN2 ----------
__global__ __launch_bounds__(256) void k5m(
    const float* __restrict__ og, const float* __restrict__ x,
    const float* __restrict__ bg,
    const u16* __restrict__ V1b, const u16* __restrict__ V2b,
    const float* __restrict__ b1, const float* __restrict__ b2,
    const float* __restrict__ g1, const float* __restrict__ be1,
    const float* __restrict__ g2, const float* __restrict__ be2,
    float* __restrict__ out, int n)
{
  __shared__ u16   lh[4][16 * 40];
  __shared__ u16   lf[4][16 * 136];
  __shared__ float lo[4][16 * 36];
  int wid = threadIdx.x >> 6, lane = threadIdx.x & 63;
  int q = lane & 15, g = lane >> 4;
  long node0 = (long)((int)blockIdx.x * 4 + wid) * 16;
  if (node0 + 16 > n) node0 = n - 16;
  u16* LH = lh[wid]; u16* LF = lf[wid]; float* LO = lo[wid];

  {
    int row = lane >> 2, off = (lane & 3) * 8;
    const float* o8 = og + (node0 + row) * CC + off;
    const float* x8 = x  + (node0 + row) * CC + off;
    float4 a0 = *(const float4*)o8, a1 = *(const float4*)(o8 + 4);
    float4 c0 = *(const float4*)x8, c1 = *(const float4*)(x8 + 4);
    float4 bg0 = *(const float4*)(bg + off), bg1 = *(const float4*)(bg + off + 4);
    float4 s0 = make_float4(a0.x + c0.x + bg0.x, a0.y + c0.y + bg0.y,
                            a0.z + c0.z + bg0.z, a0.w + c0.w + bg0.w);
    float4 s1 = make_float4(a1.x + c1.x + bg1.x, a1.y + c1.y + bg1.y,
                            a1.z + c1.z + bg1.z, a1.w + c1.w + bg1.w);
    *(float4*)(LO + row * 36 + off)     = s0;
    *(float4*)(LO + row * 36 + off + 4) = s1;
  }
  __syncthreads();

  float hv[32];
  if (lane < 16) {
#pragma unroll
    for (int i = 0; i < 8; ++i) {
      float4 t = *(const float4*)(LO + q * 36 + i * 4);
      hv[4*i] = t.x; hv[4*i+1] = t.y; hv[4*i+2] = t.z; hv[4*i+3] = t.w;
    }
    float mu = 0.f;
#pragma unroll
    for (int c = 0; c < 32; ++c) mu += hv[c];
    mu *= (1.f / 32.f);
    float var = 0.f;
#pragma unroll
    for (int c = 0; c < 32; ++c) { float t = hv[c] - mu; var = fmaf(t, t, var); }
    float rs = rsqrtf(var * (1.f / 32.f) + LNEPS);
#pragma unroll
    for (int c = 0; c < 32; ++c) hv[c] = (hv[c] - mu) * rs * g1[c] + be1[c];
    uint* dst = (uint*)(LH + q * 40);
#pragma unroll
    for (int i = 0; i < 16; ++i)
      dst[i] = bf16r(hv[2*i]) | (bf16r(hv[2*i+1]) << 16);
  }
  __syncthreads();

  bf16x8 ah = *(const bf16x8*)(LH + q * 40 + g * 8);
#pragma unroll
  for (int nb = 0; nb < 8; ++nb) {
    bf16x8 v1 = *(const bf16x8*)(V1b + nb * 512 + lane * 8);
    f32x4 acc = {0.f, 0.f, 0.f, 0.f};
    acc = __builtin_amdgcn_mfma_f32_16x16x32_bf16(ah, v1, acc, 0, 0, 0);
    int col = 16 * nb + q;
    float bias = b1[col];
#pragma unroll
    for (int r = 0; r < 4; ++r) {
      float f = fmaxf(acc[r] + bias, 0.f);
      LF[(4 * g + r) * 136 + col] = (u16)bf16r(f);
    }
  }
  __syncthreads();

  f32x4 a20 = {0.f, 0.f, 0.f, 0.f}, a21 = {0.f, 0.f, 0.f, 0.f};
#pragma unroll
  for (int kb = 0; kb < 4; ++kb) {
    bf16x8 af2 = *(const bf16x8*)(LF + q * 136 + kb * 32 + g * 8);
    bf16x8 v20 = *(const bf16x8*)(V2b + (kb * 2 + 0) * 512 + lane * 8);
    bf16x8 v21 = *(const bf16x8*)(V2b + (kb * 2 + 1) * 512 + lane * 8);
    a20 = __builtin_amdgcn_mfma_f32_16x16x32_bf16(af2, v20, a20, 0, 0, 0);
    a21 = __builtin_amdgcn_mfma_f32_16x16x32_bf16(af2, v21, a21, 0, 0, 0);
  }
  __syncthreads();
#pragma unroll
  for (int r = 0; r < 4; ++r) {
    LO[(4 * g + r) * 36 + q]      = a20[r];
    LO[(4 * g + r) * 36 + 16 + q] = a21[r];
  }
  __syncthreads();

  if (lane < 16) {
    float ov[32];
#pragma unroll
    for (int i = 0; i < 8; ++i) {
      float4 t = *(const float4*)(LO + q * 36 + i * 4);
      ov[4*i] = t.x; ov[4*i+1] = t.y; ov[4*i+2] = t.z; ov[4*i+3] = t.w;
    }
#pragma unroll
    for (int c = 0; c < 32; ++c) ov[c] += b2[c] + hv[c];
    float mu2 = 0.f;
#pragma unroll
    for (int c = 0; c < 32; ++c) mu2 += ov[c];
    mu2 *= (1.f / 32.f);
    float var2 = 0.f;
#pragma unroll
    for (int c = 0; c < 32; ++c) { float t = ov[c] - mu2; var2 = fmaf(t, t, var2); }
    float rs2 = rsqrtf(var2 * (1.f / 32.f) + LNEPS);
    float* op = out + (node0 + q) * CC;
#pragma unroll
    for (int i = 0; i < 8; ++i) {
      float4 o;
      o.x = (ov[4*i]   - mu2) * rs2 * g2[4*i]   + be2[4*i];
      o.y = (ov[4*i+1] - mu2) * rs2 * g2[4*i+1] + be2[4*i+1];
      o.z = (ov[4*i+2] - mu2) * rs2 * g2[4*i+2] + be2[4*i+2];
      o.w = (ov[4*i+3] - mu2) * rs2 * g2[4*i+3] + be2[4*i+3];
      *(float4*)(op + i * 4) = o;
    }
  }
}

// ---------- launch ----------
extern "C" void kernel_launch(void* const* d_in, const int* in_sizes, int n_in,
                              void* d_out, int out_size, void* d_ws, size_t ws_size,
                              hipStream_t stream)
{
  const float* x    = (const float*)d_in[0];
  const int*   ei   = (const int*)d_in[1];
  const float* W    = (const float*)d_in[2];
  const float* atts = (const float*)d_in[3];
  const float* attd = (const float*)d_in[4];
  const float* bg   = (const float*)d_in[5];
  const float* w1   = (const float*)d_in[6];
  const float* b1   = (const float*)d_in[7];
  const float* w2   = (const float*)d_in[8];
  const float* b2   = (const float*)d_in[9];
  const float* g1   = (const float*)d_in[10];
  const float* be1  = (const float*)d_in[11];
  const float* g2   = (const float*)d_in[12];
  const float* be2  = (const float*)d_in[13];

  int n = in_sizes[0] / CC;
  int e = in_sizes[1] / 2;

  uint8_t* ws = (uint8_t*)d_ws;
  size_t o = 0;
  unsigned* xq8 = (unsigned*)(ws + o); o += (size_t)n * 256;   // int8 rows, 256B/node
  unsigned* ascp = (unsigned*)(ws + o); o += (size_t)n * HH * 4; // bf16 a_src|fp16 scale
  float* a_d = (float*)(ws + o); o += (size_t)n * HH * 4;
  float* og  = (float*)(ws + o); o += (size_t)n * CC * 4;
  int* deg4   = (int*)(ws + o); o += (size_t)n * 4 * 4;
  int* rb     = (int*)(ws + o); o += (size_t)n * 4 * 4;
  int* degt   = (int*)(ws + o); o += (size_t)n * 4;
  unsigned* dstr = (unsigned*)(ws + o); o += (size_t)e * 4;
  int* csr    = (int*)(ws + o); o += (size_t)e * 4;
  int* bsum   = (int*)(ws + o); o += 4096;
  u16* Wb  = (u16*)(ws + o); o += 16 * 512 * 2;
  u16* Zb  = (u16*)(ws + o); o += 8 * 512 * 2;
  u16* V1b = (u16*)(ws + o); o += 8 * 512 * 2;
  u16* V2b = (u16*)(ws + o); o += 8 * 512 * 2;

  (void)hipMemsetAsync(deg4, 0, (size_t)n * 4 * 4, stream);

  int nwaves = (n + 15) / 16;
  int nbc   = (nwaves + 3) / 4;
  int nb_e4 = (e + 1023) / 1024;
  int nb_s  = (n + 1023) / 1024;
  int nb_ag = (n + 15) / 16;        // 4 waves x 4 nodes = 16 nodes per block

  khist   <<<nb_e4, 256, 0, stream>>>(ei, e, n, deg4, dstr);
  klayout <<<1, 256, 0, stream>>>(W, atts, attd, w1, w2, Wb, Zb, V1b, V2b);
  k1c     <<<nbc, 256, 0, stream>>>(x, Wb, Zb, xq8, ascp, a_d, n);
  kscanA  <<<nb_s, 256, 0, stream>>>(deg4, bsum, n);
  kscanB  <<<1, 1024, 0, stream>>>(bsum, nb_s);
  kscanC  <<<nb_s, 256, 0, stream>>>(deg4, bsum, rb, degt, n);
  kscatter<<<512, 256, 0, stream>>>(ei, dstr, e, rb, csr, n);
  kagg    <<<nb_ag, 256, 0, stream>>>(csr, rb, degt, ascp, a_d, xq8, og, n);
  k5m     <<<nbc, 256, 0, stream>>>(og, x, bg, V1b, V2b, b1, b2, g1, be1, g2, be2,
                                    (float*)d_out, n);
}

// Round 14
// 245.972 us; speedup vs baseline: 1.3355x; 1.0297x over previous
//
#include <hip/hip_runtime.h>
#include <hip/hip_fp16.h>
#include <stdint.h>

#define HH 8
#define CC 32
#define HC 256   // H*C
#define FF 128
#define NEG 0.2f
#define LNEPS 1e-5f

typedef __attribute__((ext_vector_type(8))) short bf16x8;
typedef __attribute__((ext_vector_type(4))) float f32x4;
typedef unsigned short u16;

// ---------- helpers ----------
__device__ inline unsigned bf16r(float f) {           // round-to-nearest-even bf16
  unsigned u = __float_as_uint(f);
  return (u + 0x7fffu + ((u >> 16) & 1u)) >> 16;
}
__device__ inline float bflo(unsigned w) { return __uint_as_float(w << 16); }
__device__ inline float bfhi(unsigned w) { return __uint_as_float(w & 0xffff0000u); }
__device__ inline float leaky(float v) { return v >= 0.f ? v : NEG * v; }
__device__ inline float h2f(unsigned hbits) {
  return __half2float(__ushort_as_half((unsigned short)hbits));
}
__device__ inline u16 f2h(float f) {
  return __half_as_ushort(__float2half(f));
}
// byte extract -> float (v_cvt_f32_ubyte0..3)
__device__ inline float ub0(unsigned w) { return (float)(w & 0xffu); }
__device__ inline float ub1(unsigned w) { return (float)((w >> 8) & 0xffu); }
__device__ inline float ub2(unsigned w) { return (float)((w >> 16) & 0xffu); }
__device__ inline float ub3(unsigned w) { return (float)(w >> 24); }

// ---------- KLAYOUT: repack weights into MFMA B-fragment layout (bf16) ----------
__global__ __launch_bounds__(256) void klayout(
    const float* __restrict__ W, const float* __restrict__ atts,
    const float* __restrict__ attd, const float* __restrict__ w1,
    const float* __restrict__ w2,
    u16* __restrict__ Wb, u16* __restrict__ Zb,
    u16* __restrict__ V1b, u16* __restrict__ V2b, u16* __restrict__ WSb)
{
  int t = threadIdx.x;
  for (int i = t; i < 16 * 512; i += 256) {        // Wb: W_gat [32,256]
    int j = i & 7, l = (i >> 3) & 63, nb = i >> 9;
    int k = 8 * (l >> 4) + j, c = 16 * nb + (l & 15);
    Wb[i] = (u16)bf16r(W[k * HC + c]);
  }
  for (int i = t; i < 8 * 512; i += 256) {         // Zb: [256,16] = [atts|attd] blockdiag
    int j = i & 7, l = (i >> 3) & 63, kb = i >> 9;
    int k = 32 * kb + 8 * (l >> 4) + j;
    int tc = l & 15;
    float v = 0.f;
    if (tc < 8)  { if ((k >> 5) == tc)     v = atts[tc * 32 + (k & 31)]; }
    else         { if ((k >> 5) == tc - 8) v = attd[(tc - 8) * 32 + (k & 31)]; }
    Zb[i] = (u16)bf16r(v);
  }
  for (int i = t; i < 8 * 512; i += 256) {         // V1b: w1 [32,128]
    int j = i & 7, l = (i >> 3) & 63, nb = i >> 9;
    int k = 8 * (l >> 4) + j, c = 16 * nb + (l & 15);
    V1b[i] = (u16)bf16r(w1[k * FF + c]);
  }
  for (int i = t; i < 8 * 512; i += 256) {         // V2b: w2 [128,32]
    int j = i & 7, l = (i >> 3) & 63, kn = i >> 9;
    int kb = kn >> 1, nb2 = kn & 1;
    int k = 32 * kb + 8 * (l >> 4) + j, c = 16 * nb2 + (l & 15);
    V2b[i] = (u16)bf16r(w2[k * CC + c]);
  }
  for (int i = t; i < 16 * 512; i += 256) {        // WSb: Wstack [256,32],
    int j = i & 7, l = (i >> 3) & 63, kn = i >> 9; // Wstack[h*32+k][c]=W[k][h*32+c]
    int kb = kn >> 1, nb2 = kn & 1;
    int krow = kb * 32 + 8 * (l >> 4) + j;         // 0..255
    int h = krow >> 5, kk = krow & 31;
    int c = 16 * nb2 + (l & 15);
    WSb[i] = (u16)bf16r(W[kk * HC + h * 32 + c]);
  }
}

// ---------- KHIST: replicated-counter histogram + (replica, rank) emit ----------
__global__ __launch_bounds__(256) void khist(
    const int* __restrict__ ei, int e, int n,
    int* __restrict__ deg4, unsigned* __restrict__ dstr)
{
  int r = (int)blockIdx.x & 3;
  int* dr = deg4 + (size_t)r * n;
  int i = (int)blockIdx.x * 1024 + (int)threadIdx.x * 4;
  if (i >= e) return;
  const int* dst = ei + e;
  if (i + 3 < e) {
    int4 d4 = *(const int4*)(dst + i);
    unsigned r0 = (unsigned)atomicAdd(&dr[d4.x], 1);
    unsigned r1 = (unsigned)atomicAdd(&dr[d4.y], 1);
    unsigned r2 = (unsigned)atomicAdd(&dr[d4.z], 1);
    unsigned r3 = (unsigned)atomicAdd(&dr[d4.w], 1);
    uint4 o;
    o.x = (unsigned)d4.x | ((unsigned)r << 17) | (r0 << 19);
    o.y = (unsigned)d4.y | ((unsigned)r << 17) | (r1 << 19);
    o.z = (unsigned)d4.z | ((unsigned)r << 17) | (r2 << 19);
    o.w = (unsigned)d4.w | ((unsigned)r << 17) | (r3 << 19);
    *(uint4*)(dstr + i) = o;
  } else {
    for (int k = 0; k < 4 && i + k < e; ++k) {
      int d = dst[i + k];
      unsigned rr = (unsigned)atomicAdd(&dr[d], 1);
      dstr[i + k] = (unsigned)d | ((unsigned)r << 17) | (rr << 19);
    }
  }
}

// ---------- K1C: MFMA (xp in LDS only) -> a_src/a_dst dots + int8-quantized x ----------
__global__ __launch_bounds__(256) void k1c(
    const float* __restrict__ x, const u16* __restrict__ Wb,
    const u16* __restrict__ Zb,
    unsigned* __restrict__ xqx, unsigned* __restrict__ ascp,
    float* __restrict__ a_d, int n)
{
  __shared__ u16 lt[4][16 * 264];                  // per-wave [16 rows][264 halfs]
  int wid = threadIdx.x >> 6, lane = threadIdx.x & 63;
  int q = lane & 15, g = lane >> 4;
  long node0 = (long)((int)blockIdx.x * 4 + wid) * 16;
  if (node0 + 16 > n) node0 = n - 16;              // overlap tail: duplicate identical writes
  u16* L = lt[wid];
  u16* ascp16 = (u16*)ascp;

  // A-frag: x[node0+q][8g..8g+7] -> bf16; keep fp32 copies for quantization
  const float* xr = x + (node0 + q) * CC + 8 * g;
  float4 xa = *(const float4*)xr, xb = *(const float4*)(xr + 4);
  bf16x8 af;
  af[0] = (short)bf16r(xa.x); af[1] = (short)bf16r(xa.y);
  af[2] = (short)bf16r(xa.z); af[3] = (short)bf16r(xa.w);
  af[4] = (short)bf16r(xb.x); af[5] = (short)bf16r(xb.y);
  af[6] = (short)bf16r(xb.z); af[7] = (short)bf16r(xb.w);

  // ---- per-node x absmax over 32 ch (4 lanes share q: xor 16, 32) ----
  float mx = fmaxf(fmaxf(fmaxf(fabsf(xa.x), fabsf(xa.y)), fmaxf(fabsf(xa.z), fabsf(xa.w))),
                   fmaxf(fmaxf(fabsf(xb.x), fabsf(xb.y)), fmaxf(fabsf(xb.z), fabsf(xb.w))));
  mx = fmaxf(mx, __shfl_xor(mx, 16));
  mx = fmaxf(mx, __shfl_xor(mx, 32));
  float rinv = (mx > 0.f) ? 127.f / mx : 0.f;
  u16 sch = f2h(mx * (1.f / 127.f));
  // scale -> ascp hi16, replicated in all 8 head slots (heads 2g, 2g+1 per lane)
  ascp16[((node0 + q) * HH + 2 * g) * 2 + 1]     = sch;
  ascp16[((node0 + q) * HH + 2 * g + 1) * 2 + 1] = sch;
  // int8 encode x -> xqx (row = 8 dwords; lane stores dwords 2g, 2g+1)
  {
    int q0 = min(max(__float2int_rn(xa.x * rinv), -127), 127) + 128;
    int q1 = min(max(__float2int_rn(xa.y * rinv), -127), 127) + 128;
    int q2 = min(max(__float2int_rn(xa.z * rinv), -127), 127) + 128;
    int q3 = min(max(__float2int_rn(xa.w * rinv), -127), 127) + 128;
    int q4 = min(max(__float2int_rn(xb.x * rinv), -127), 127) + 128;
    int q5 = min(max(__float2int_rn(xb.y * rinv), -127), 127) + 128;
    int q6 = min(max(__float2int_rn(xb.z * rinv), -127), 127) + 128;
    int q7 = min(max(__float2int_rn(xb.w * rinv), -127), 127) + 128;
    uint2 pk;
    pk.x = (unsigned)q0 | ((unsigned)q1 << 8) | ((unsigned)q2 << 16) | ((unsigned)q3 << 24);
    pk.y = (unsigned)q4 | ((unsigned)q5 << 8) | ((unsigned)q6 << 16) | ((unsigned)q7 << 24);
    *(uint2*)(xqx + (node0 + q) * 8 + 2 * g) = pk;
  }

  // ---- xp = x@W into LDS (needed only for the a-dots) ----
#pragma unroll
  for (int nb = 0; nb < 16; ++nb) {
    bf16x8 bf = *(const bf16x8*)(Wb + nb * 512 + lane * 8);
    f32x4 acc = {0.f, 0.f, 0.f, 0.f};
    acc = __builtin_amdgcn_mfma_f32_16x16x32_bf16(af, bf, acc, 0, 0, 0);
    int col = 16 * nb + q;
#pragma unroll
    for (int r = 0; r < 4; ++r)
      L[(4 * g + r) * 264 + col] = (u16)bf16r(acc[r]);
  }
  __syncthreads();

  // a_src/a_dst: [16 nodes,256] x [256,16] via 8 chained mfma
  f32x4 az = {0.f, 0.f, 0.f, 0.f};
#pragma unroll
  for (int kb = 0; kb < 8; ++kb) {
    bf16x8 a2 = *(const bf16x8*)(L + q * 264 + kb * 32 + g * 8);
    bf16x8 zb = *(const bf16x8*)(Zb + kb * 512 + lane * 8);
    az = __builtin_amdgcn_mfma_f32_16x16x32_bf16(a2, zb, az, 0, 0, 0);
  }
  int hq = q & 7;
  if (q < 8) {                                     // a_src -> ascp lo16 (bf16)
#pragma unroll
    for (int r = 0; r < 4; ++r)
      ascp16[((node0 + 4 * g + r) * HH + hq) * 2] = (u16)bf16r(az[r]);
  } else {                                         // a_dst (fp32)
#pragma unroll
    for (int r = 0; r < 4; ++r)
      a_d[(node0 + 4 * g + r) * HH + hq] = az[r];
  }
}

// ---------- scan phase A: per-1024-block sums (over 4 replicas) ----------
__global__ __launch_bounds__(256) void kscanA(const int* __restrict__ deg4,
                                              int* __restrict__ bsum, int n)
{
  __shared__ int ws[4];
  int t = threadIdx.x;
  int i = (int)blockIdx.x * 1024 + t * 4;
  int s = 0;
  if (i + 3 < n) {
#pragma unroll
    for (int r = 0; r < 4; ++r) {
      int4 v = *(const int4*)(deg4 + (size_t)r * n + i);
      s += v.x + v.y + v.z + v.w;
    }
  } else {
    for (int k = 0; k < 4 && i + k < n; ++k)
#pragma unroll
      for (int r = 0; r < 4; ++r) s += deg4[(size_t)r * n + i + k];
  }
#pragma unroll
  for (int mask = 1; mask < 64; mask <<= 1) s += __shfl_xor(s, mask);
  if ((t & 63) == 0) ws[t >> 6] = s;
  __syncthreads();
  if (t == 0) bsum[blockIdx.x] = ws[0] + ws[1] + ws[2] + ws[3];
}

// ---------- scan phase B ----------
__global__ __launch_bounds__(1024) void kscanB(int* __restrict__ bsum, int nb)
{
  __shared__ int wsum[16];
  int t = threadIdx.x, lane = t & 63, wid = t >> 6;
  int v = (t < nb) ? bsum[t] : 0;
  int s = v;
#pragma unroll
  for (int d = 1; d < 64; d <<= 1) { int tt = __shfl_up(s, d); if (lane >= d) s += tt; }
  if (lane == 63) wsum[wid] = s;
  __syncthreads();
  if (wid == 0) {
    int w = (lane < 16) ? wsum[lane] : 0;
#pragma unroll
    for (int d = 1; d < 16; d <<= 1) { int tt = __shfl_up(w, d); if (lane >= d) w += tt; }
    if (lane < 16) wsum[lane] = w;
  }
  __syncthreads();
  int excl = s - v + ((wid > 0) ? wsum[wid - 1] : 0);
  if (t < nb) bsum[t] = excl;
}

// ---------- scan phase C: offs (=rb[0]) + per-replica bases rb[1..3] + degt ----------
__global__ __launch_bounds__(256) void kscanC(const int* __restrict__ deg4,
                                              const int* __restrict__ bsum,
                                              int* __restrict__ rb,
                                              int* __restrict__ degt, int n)
{
  __shared__ int ws[4];
  int t = threadIdx.x, lane = t & 63, wid = t >> 6;
  int i = (int)blockIdx.x * 1024 + t * 4;
  int c0[4] = {0,0,0,0}, c1[4] = {0,0,0,0}, c2[4] = {0,0,0,0}, c3[4] = {0,0,0,0};
  if (i + 3 < n) {
    int4 v0 = *(const int4*)(deg4 + 0 * (size_t)n + i);
    int4 v1 = *(const int4*)(deg4 + 1 * (size_t)n + i);
    int4 v2 = *(const int4*)(deg4 + 2 * (size_t)n + i);
    int4 v3 = *(const int4*)(deg4 + 3 * (size_t)n + i);
    c0[0]=v0.x;c0[1]=v0.y;c0[2]=v0.z;c0[3]=v0.w;
    c1[0]=v1.x;c1[1]=v1.y;c1[2]=v1.z;c1[3]=v1.w;
    c2[0]=v2.x;c2[1]=v2.y;c2[2]=v2.z;c2[3]=v2.w;
    c3[0]=v3.x;c3[1]=v3.y;c3[2]=v3.z;c3[3]=v3.w;
  } else {
    for (int k = 0; k < 4 && i + k < n; ++k) {
      c0[k] = deg4[0 * (size_t)n + i + k];
      c1[k] = deg4[1 * (size_t)n + i + k];
      c2[k] = deg4[2 * (size_t)n + i + k];
      c3[k] = deg4[3 * (size_t)n + i + k];
    }
  }
  int tot[4];
#pragma unroll
  for (int k = 0; k < 4; ++k) tot[k] = c0[k] + c1[k] + c2[k] + c3[k];
  int tsum = tot[0] + tot[1] + tot[2] + tot[3];
  int s = tsum;
#pragma unroll
  for (int d = 1; d < 64; d <<= 1) { int tt = __shfl_up(s, d); if (lane >= d) s += tt; }
  if (lane == 63) ws[wid] = s;
  __syncthreads();
  if (t == 0) {
    int a = ws[0]; ws[0] = 0;
    int b = ws[1]; ws[1] = a; a += b;
    int c = ws[2]; ws[2] = a; a += c;
    ws[3] = a;
  }
  __syncthreads();
  int base = bsum[blockIdx.x] + ws[wid] + (s - tsum);
#pragma unroll
  for (int k = 0; k < 4; ++k) {
    if (i + k < n) {
      int b0 = base;
      rb[0 * (size_t)n + i + k] = b0;
      rb[1 * (size_t)n + i + k] = b0 + c0[k];
      rb[2 * (size_t)n + i + k] = b0 + c0[k] + c1[k];
      rb[3 * (size_t)n + i + k] = b0 + c0[k] + c1[k] + c2[k];
      degt[i + k] = tot[k];
    }
    base += tot[k];
  }
}

// ---------- CSR scatter: rank-based, ATOMIC-FREE, dst-quadrant L2-local writes ----------
__global__ __launch_bounds__(256) void kscatter(
    const int* __restrict__ ei, const unsigned* __restrict__ dstr, int e,
    const int* __restrict__ rb, int* __restrict__ csr, int n)
{
  int oct = (int)blockIdx.x & 3;
  int nsub = (int)gridDim.x >> 2;
  int sub = (int)blockIdx.x >> 2;
  int nper = (n + 3) >> 2;
  int lo = oct * nper, hi = lo + nper;
  int stride = nsub << 10;
  for (int i = (sub * 256 + (int)threadIdx.x) * 4; i < e; i += stride) {
    if (i + 3 < e) {
      uint4 d4 = *(const uint4*)(dstr + i);
      int4 s4 = *(const int4*)(ei + i);
      int dx = d4.x & 0x1ffff, dy = d4.y & 0x1ffff,
          dz = d4.z & 0x1ffff, dw = d4.w & 0x1ffff;
      if (dx >= lo && dx < hi)
        csr[rb[(size_t)((d4.x >> 17) & 3) * n + dx] + (d4.x >> 19)] = s4.x;
      if (dy >= lo && dy < hi)
        csr[rb[(size_t)((d4.y >> 17) & 3) * n + dy] + (d4.y >> 19)] = s4.y;
      if (dz >= lo && dz < hi)
        csr[rb[(size_t)((d4.z >> 17) & 3) * n + dz] + (d4.z >> 19)] = s4.z;
      if (dw >= lo && dw < hi)
        csr[rb[(size_t)((d4.w >> 17) & 3) * n + dw] + (d4.w >> 19)] = s4.w;
    } else {
      for (int k = 0; k < 4 && i + k < e; ++k) {
        unsigned dv = dstr[i + k];
        int d = dv & 0x1ffff;
        if (d >= lo && d < hi)
          csr[rb[(size_t)((dv >> 17) & 3) * n + d] + (dv >> 19)] = ei[i + k];
      }
    }
  }
}

// ---------- KAGG: aggregate RAW x (int8, 32B/row) with per-head attn; agg bf16 out ----------
// out[d] = (1/8) Sum_h (Sum_src attn_h x[src]) @ W_h  — the @W happens in k5m.
// A-layout: eg=lane>>3 (edge in chunk), ha=lane&7 (head) — compute p, p*xscale.
// B-layout: hb=lane>>3 (head), c4=(lane&7) — gather x dword c4, accumulate agg[hb][c4*4..+3].
__global__ __launch_bounds__(256) void kagg(
    const int* __restrict__ csr, const int* __restrict__ offs,
    const int* __restrict__ degt,
    const unsigned* __restrict__ ascp, const float* __restrict__ a_d,
    const unsigned* __restrict__ xqx, unsigned* __restrict__ agg32, int n)
{
  int lane = threadIdx.x & 63;
  int wid  = threadIdx.x >> 6;
  int base = ((int)blockIdx.x * 4 + wid) * 4;      // 4 nodes per wave
  int eg = lane >> 3, ha = lane & 7;
  int hb = eg;
  int c4 = lane & 7;

  for (int t = 0; t < 4; ++t) {
    int node = base + t;
    if (node >= n) return;
    int start = offs[node];
    int dg = degt[node];
    unsigned aw_self = ascp[(size_t)node * HH + ha];
    float ad_a  = a_d[(size_t)node * HH + ha];
    float aself = leaky(bflo(aw_self) + ad_a);

    float acc0 = 0.f, acc1 = 0.f, acc2 = 0.f, acc3 = 0.f;
    float dnA = 0.f, osA = 0.f;

    for (int j0 = 0; j0 < dg; j0 += 8) {
      int cnt = dg - j0; if (cnt > 8) cnt = 8;
      int idx = j0 + eg;
      int srcl = 0; float pw = 0.f;
      if (idx < dg) {
        srcl = csr[start + idx];
        unsigned av = ascp[(size_t)srcl * HH + ha];
        float al = leaky(bflo(av) + ad_a);
        float p  = __expf(al - aself);
        pw = p * h2f(av >> 16);                    // p * xscale_src
        dnA += p; osA += pw;
      }
      if (cnt == 8) {
#pragma unroll
        for (int j = 0; j < 8; ++j) {
          float wt = __shfl(pw, (j << 3) + hb);
          int s = __shfl(srcl, j << 3);
          unsigned w = xqx[(size_t)s * 8 + c4];
          acc0 = fmaf(ub0(w), wt, acc0);
          acc1 = fmaf(ub1(w), wt, acc1);
          acc2 = fmaf(ub2(w), wt, acc2);
          acc3 = fmaf(ub3(w), wt, acc3);
        }
      } else {
        for (int j = 0; j < cnt; ++j) {
          float wt = __shfl(pw, (j << 3) + hb);
          int s = __shfl(srcl, j << 3);
          unsigned w = xqx[(size_t)s * 8 + c4];
          acc0 = fmaf(ub0(w), wt, acc0);
          acc1 = fmaf(ub1(w), wt, acc1);
          acc2 = fmaf(ub2(w), wt, acc2);
          acc3 = fmaf(ub3(w), wt, acc3);
        }
      }
    }

    // reduce dn/osum over edge-slot dim (eg): after this, value is per-head ha
    float dnH = dnA, osH = osA;
    dnH += __shfl_xor(dnH, 8);  osH += __shfl_xor(osH, 8);
    dnH += __shfl_xor(dnH, 16); osH += __shfl_xor(osH, 16);
    dnH += __shfl_xor(dnH, 32); osH += __shfl_xor(osH, 32);
    float dnB = __shfl(dnH, hb);
    float osB = __shfl(osH, hb);
    float scB = __shfl(h2f(aw_self >> 16), hb);    // xscale_node (replicated)

    // self loop: p = 1
    {
      unsigned w = xqx[(size_t)node * 8 + c4];
      dnB += 1.f; osB += scB;
      acc0 = fmaf(ub0(w), scB, acc0);
      acc1 = fmaf(ub1(w), scB, acc1);
      acc2 = fmaf(ub2(w), scB, acc2);
      acc3 = fmaf(ub3(w), scB, acc3);
    }

    float corr = -128.f * osB;
    float inv = 0.125f / dnB;                      // fold 1/8 head-mean here
    acc0 = (acc0 + corr) * inv;
    acc1 = (acc1 + corr) * inv;
    acc2 = (acc2 + corr) * inv;
    acc3 = (acc3 + corr) * inv;
    // store agg bf16: j = hb*32 + c4*4 + k -> dword index hb*16 + c4*2
    uint2 pk;
    pk.x = bf16r(acc0) | (bf16r(acc1) << 16);
    pk.y = bf16r(acc2) | (bf16r(acc3) << 16);
    *(uint2*)(agg32 + (size_t)node * 128 + hb * 16 + c4 * 2) = pk;
  }
}

// ---------- K5M: MFMA tail — og = agg@Wstack, + x + bg, LN1 + FFN(mfma) + LN2 ----------
__global__ __launch_bounds__(256) void k5m(
    const u16* __restrict__ agg16, const float* __restrict__ x,
    const float* __restrict__ bg, const u16* __restrict__ WSb,
    const u16* __restrict__ V1b, const u16* __restrict__ V2b,
    const float* __restrict__ b1, const float* __restrict__ b2,
    const float* __restrict__ g1, const float* __restrict__ be1,
    const float* __restrict__ g2, const float* __restrict__ be2,
    float* __restrict__ out, int n)
{
  __shared__ u16   lh[4][16 * 40];
  __shared__ u16   lf[4][16 * 136];
  __shared__ float lo[4][16 * 36];
  int wid = threadIdx.x >> 6, lane = threadIdx.x & 63;
  int q = lane & 15, g = lane >> 4;
  long node0 = (long)((int)blockIdx.x * 4 + wid) * 16;
  if (node0 + 16 > n) node0 = n - 16;
  u16* LH = lh[wid]; u16* LF = lf[wid]; float* LO = lo[wid];

  // stage x + bg cooperatively
  {
    int row = lane >> 2, off = (lane & 3) * 8;
    const float* x8 = x + (node0 + row) * CC + off;
    float4 c0 = *(const float4*)x8, c1 = *(const float4*)(x8 + 4);
    float4 bg0 = *(const float4*)(bg + off), bg1 = *(const float4*)(bg + off + 4);
    float4 s0 = make_float4(c0.x + bg0.x, c0.y + bg0.y, c0.z + bg0.z, c0.w + bg0.w);
    float4 s1 = make_float4(c1.x + bg1.x, c1.y + bg1.y, c1.z + bg1.z, c1.w + bg1.w);
    *(float4*)(LO + row * 36 + off)     = s0;
    *(float4*)(LO + row * 36 + off + 4) = s1;
  }
  __syncthreads();

  // og = agg @ Wstack  ([16,256] x [256,32]) then LO += og
  {
    f32x4 a20 = {0.f, 0.f, 0.f, 0.f}, a21 = {0.f, 0.f, 0.f, 0.f};
#pragma unroll
    for (int kb = 0; kb < 8; ++kb) {
      bf16x8 af = *(const bf16x8*)(agg16 + (node0 + q) * 256 + kb * 32 + g * 8);
      bf16x8 w0 = *(const bf16x8*)(WSb + (kb * 2 + 0) * 512 + lane * 8);
      bf16x8 w1v = *(const bf16x8*)(WSb + (kb * 2 + 1) * 512 + lane * 8);
      a20 = __builtin_amdgcn_mfma_f32_16x16x32_bf16(af, w0, a20, 0, 0, 0);
      a21 = __builtin_amdgcn_mfma_f32_16x16x32_bf16(af, w1v, a21, 0, 0, 0);
    }
#pragma unroll
    for (int r = 0; r < 4; ++r) {
      LO[(4 * g + r) * 36 + q]      += a20[r];
      LO[(4 * g + r) * 36 + 16 + q] += a21[r];
    }
  }
  __syncthreads();

  float hv[32];
  if (lane < 16) {
#pragma unroll
    for (int i = 0; i < 8; ++i) {
      float4 t = *(const float4*)(LO + q * 36 + i * 4);
      hv[4*i] = t.x; hv[4*i+1] = t.y; hv[4*i+2] = t.z; hv[4*i+3] = t.w;
    }
    float mu = 0.f;
#pragma unroll
    for (int c = 0; c < 32; ++c) mu += hv[c];
    mu *= (1.f / 32.f);
    float var = 0.f;
#pragma unroll
    for (int c = 0; c < 32; ++c) { float t = hv[c] - mu; var = fmaf(t, t, var); }
    float rs = rsqrtf(var * (1.f / 32.f) + LNEPS);
#pragma unroll
    for (int c = 0; c < 32; ++c) hv[c] = (hv[c] - mu) * rs * g1[c] + be1[c];
    uint* dst = (uint*)(LH + q * 40);
#pragma unroll
    for (int i = 0; i < 16; ++i)
      dst[i] = bf16r(hv[2*i]) | (bf16r(hv[2*i+1]) << 16);
  }
  __syncthreads();

  bf16x8 ah = *(const bf16x8*)(LH + q * 40 + g * 8);
#pragma unroll
  for (int nb = 0; nb < 8; ++nb) {
    bf16x8 v1 = *(const bf16x8*)(V1b + nb * 512 + lane * 8);
    f32x4 acc = {0.f, 0.f, 0.f, 0.f};
    acc = __builtin_amdgcn_mfma_f32_16x16x32_bf16(ah, v1, acc, 0, 0, 0);
    int col = 16 * nb + q;
    float bias = b1[col];
#pragma unroll
    for (int r = 0; r < 4; ++r) {
      float f = fmaxf(acc[r] + bias, 0.f);
      LF[(4 * g + r) * 136 + col] = (u16)bf16r(f);
    }
  }
  __syncthreads();

  f32x4 a20 = {0.f, 0.f, 0.f, 0.f}, a21 = {0.f, 0.f, 0.f, 0.f};
#pragma unroll
  for (int kb = 0; kb < 4; ++kb) {
    bf16x8 af2 = *(const bf16x8*)(LF + q * 136 + kb * 32 + g * 8);
    bf16x8 v20 = *(const bf16x8*)(V2b + (kb * 2 + 0) * 512 + lane * 8);
    bf16x8 v21 = *(const bf16x8*)(V2b + (kb * 2 + 1) * 512 + lane * 8);
    a20 = __builtin_amdgcn_mfma_f32_16x16x32_bf16(af2, v20, a20, 0, 0, 0);
    a21 = __builtin_amdgcn_mfma_f32_16x16x32_bf16(af2, v21, a21, 0, 0, 0);
  }
  __syncthreads();
#pragma unroll
  for (int r = 0; r < 4; ++r) {
    LO[(4 * g + r) * 36 + q]      = a20[r];
    LO[(4 * g + r) * 36 + 16 + q] = a21[r];
  }
  __syncthreads();

  if (lane < 16) {
    float ov[32];
#pragma unroll
    for (int i = 0; i < 8; ++i) {
      float4 t = *(const float4*)(LO + q * 36 + i * 4);
      ov[4*i] = t.x; ov[4*i+1] = t.y; ov[4*i+2] = t.z; ov[4*i+3] = t.w;
    }
#pragma unroll
    for (int c = 0; c < 32; ++c) ov[c] += b2[c] + hv[c];
    float mu2 = 0.f;
#pragma unroll
    for (int c = 0; c < 32; ++c) mu2 += ov[c];
    mu2 *= (1.f / 32.f);
    float var2 = 0.f;
#pragma unroll
    for (int c = 0; c < 32; ++c) { float t = ov[c] - mu2; var2 = fmaf(t, t, var2); }
    float rs2 = rsqrtf(var2 * (1.f / 32.f) + LNEPS);
    float* op = out + (node0 + q) * CC;
#pragma unroll
    for (int i = 0; i < 8; ++i) {
      float4 o;
      o.x = (ov[4*i]   - mu2) * rs2 * g2[4*i]   + be2[4*i];
      o.y = (ov[4*i+1] - mu2) * rs2 * g2[4*i+1] + be2[4*i+1];
      o.z = (ov[4*i+2] - mu2) * rs2 * g2[4*i+2] + be2[4*i+2];
      o.w = (ov[4*i+3] - mu2) * rs2 * g2[4*i+3] + be2[4*i+3];
      *(float4*)(op + i * 4) = o;
    }
  }
}

// ---------- launch ----------
extern "C" void kernel_launch(void* const* d_in, const int* in_sizes, int n_in,
                              void* d_out, int out_size, void* d_ws, size_t ws_size,
                              hipStream_t stream)
{
  const float* x    = (const float*)d_in[0];
  const int*   ei   = (const int*)d_in[1];
  const float* W    = (const float*)d_in[2];
  const float* atts = (const float*)d_in[3];
  const float* attd = (const float*)d_in[4];
  const float* bg   = (const float*)d_in[5];
  const float* w1   = (const float*)d_in[6];
  const float* b1   = (const float*)d_in[7];
  const float* w2   = (const float*)d_in[8];
  const float* b2   = (const float*)d_in[9];
  const float* g1   = (const float*)d_in[10];
  const float* be1  = (const float*)d_in[11];
  const float* g2   = (const float*)d_in[12];
  const float* be2  = (const float*)d_in[13];

  int n = in_sizes[0] / CC;
  int e = in_sizes[1] / 2;

  uint8_t* ws = (uint8_t*)d_ws;
  size_t o = 0;
  unsigned* xqx = (unsigned*)(ws + o); o += (size_t)n * 32;      // int8 x rows, 32B/node
  unsigned* ascp = (unsigned*)(ws + o); o += (size_t)n * HH * 4; // bf16 a_src|fp16 xscale
  float* a_d = (float*)(ws + o); o += (size_t)n * HH * 4;
  unsigned* agg32 = (unsigned*)(ws + o); o += (size_t)n * 512;   // bf16 agg [N,256]
  int* deg4   = (int*)(ws + o); o += (size_t)n * 4 * 4;
  int* rb     = (int*)(ws + o); o += (size_t)n * 4 * 4;
  int* degt   = (int*)(ws + o); o += (size_t)n * 4;
  unsigned* dstr = (unsigned*)(ws + o); o += (size_t)e * 4;
  int* csr    = (int*)(ws + o); o += (size_t)e * 4;
  int* bsum   = (int*)(ws + o); o += 4096;
  u16* Wb  = (u16*)(ws + o); o += 16 * 512 * 2;
  u16* Zb  = (u16*)(ws + o); o += 8 * 512 * 2;
  u16* V1b = (u16*)(ws + o); o += 8 * 512 * 2;
  u16* V2b = (u16*)(ws + o); o += 8 * 512 * 2;
  u16* WSb = (u16*)(ws + o); o += 16 * 512 * 2;

  (void)hipMemsetAsync(deg4, 0, (size_t)n * 4 * 4, stream);

  int nwaves = (n + 15) / 16;
  int nbc   = (nwaves + 3) / 4;
  int nb_e4 = (e + 1023) / 1024;
  int nb_s  = (n + 1023) / 1024;
  int nb_ag = (n + 15) / 16;        // 4 waves x 4 nodes = 16 nodes per block

  khist   <<<nb_e4, 256, 0, stream>>>(ei, e, n, deg4, dstr);
  klayout <<<1, 256, 0, stream>>>(W, atts, attd, w1, w2, Wb, Zb, V1b, V2b, WSb);
  k1c     <<<nbc, 256, 0, stream>>>(x, Wb, Zb, xqx, ascp, a_d, n);
  kscanA  <<<nb_s, 256, 0, stream>>>(deg4, bsum, n);
  kscanB  <<<1, 1024, 0, stream>>>(bsum, nb_s);
  kscanC  <<<nb_s, 256, 0, stream>>>(deg4, bsum, rb, degt, n);
  kscatter<<<512, 256, 0, stream>>>(ei, dstr, e, rb, csr, n);
  kagg    <<<nb_ag, 256, 0, stream>>>(csr, rb, degt, ascp, a_d, xqx, agg32, n);
  k5m     <<<nbc, 256, 0, stream>>>((const u16*)agg32, x, bg, WSb, V1b, V2b,
                                    b1, b2, g1, be1, g2, be2, (float*)d_out, n);
}

// Round 15
// 231.119 us; speedup vs baseline: 1.4213x; 1.0643x over previous
//
#include <hip/hip_runtime.h>
#include <hip/hip_fp16.h>
#include <stdint.h>

#define HH 8
#define CC 32
#define HC 256   // H*C
#define FF 128
#define NEG 0.2f
#define LNEPS 1e-5f

typedef __attribute__((ext_vector_type(8))) short bf16x8;
typedef __attribute__((ext_vector_type(4))) float f32x4;
typedef unsigned short u16;

// ---------- helpers ----------
__device__ inline unsigned bf16r(float f) {           // round-to-nearest-even bf16
  unsigned u = __float_as_uint(f);
  return (u + 0x7fffu + ((u >> 16) & 1u)) >> 16;
}
__device__ inline float bflo(unsigned w) { return __uint_as_float(w << 16); }
__device__ inline float bfhi(unsigned w) { return __uint_as_float(w & 0xffff0000u); }
__device__ inline float leaky(float v) { return v >= 0.f ? v : NEG * v; }
__device__ inline float h2f(unsigned hbits) {
  return __half2float(__ushort_as_half((unsigned short)hbits));
}
__device__ inline u16 f2h(float f) {
  return __half_as_ushort(__float2half(f));
}
// byte extract -> float (v_cvt_f32_ubyte0..3)
__device__ inline float ub0(unsigned w) { return (float)(w & 0xffu); }
__device__ inline float ub1(unsigned w) { return (float)((w >> 8) & 0xffu); }
__device__ inline float ub2(unsigned w) { return (float)((w >> 16) & 0xffu); }
__device__ inline float ub3(unsigned w) { return (float)(w >> 24); }

// ---------- KLAYOUT: repack weights into MFMA B-fragment layout (bf16) ----------
__global__ __launch_bounds__(256) void klayout(
    const float* __restrict__ W, const float* __restrict__ atts,
    const float* __restrict__ attd, const float* __restrict__ w1,
    const float* __restrict__ w2,
    u16* __restrict__ Wb, u16* __restrict__ Zb,
    u16* __restrict__ V1b, u16* __restrict__ V2b, u16* __restrict__ WSb)
{
  int t0 = (int)blockIdx.x * 256 + (int)threadIdx.x;
  int st = (int)gridDim.x * 256;
  for (int i = t0; i < 16 * 512; i += st) {        // Wb: W_gat [32,256]
    int j = i & 7, l = (i >> 3) & 63, nb = i >> 9;
    int k = 8 * (l >> 4) + j, c = 16 * nb + (l & 15);
    Wb[i] = (u16)bf16r(W[k * HC + c]);
  }
  for (int i = t0; i < 8 * 512; i += st) {         // Zb: [256,16] = [atts|attd] blockdiag
    int j = i & 7, l = (i >> 3) & 63, kb = i >> 9;
    int k = 32 * kb + 8 * (l >> 4) + j;
    int tc = l & 15;
    float v = 0.f;
    if (tc < 8)  { if ((k >> 5) == tc)     v = atts[tc * 32 + (k & 31)]; }
    else         { if ((k >> 5) == tc - 8) v = attd[(tc - 8) * 32 + (k & 31)]; }
    Zb[i] = (u16)bf16r(v);
  }
  for (int i = t0; i < 8 * 512; i += st) {         // V1b: w1 [32,128]
    int j = i & 7, l = (i >> 3) & 63, nb = i >> 9;
    int k = 8 * (l >> 4) + j, c = 16 * nb + (l & 15);
    V1b[i] = (u16)bf16r(w1[k * FF + c]);
  }
  for (int i = t0; i < 8 * 512; i += st) {         // V2b: w2 [128,32]
    int j = i & 7, l = (i >> 3) & 63, kn = i >> 9;
    int kb = kn >> 1, nb2 = kn & 1;
    int k = 32 * kb + 8 * (l >> 4) + j, c = 16 * nb2 + (l & 15);
    V2b[i] = (u16)bf16r(w2[k * CC + c]);
  }
  for (int i = t0; i < 16 * 512; i += st) {        // WSb: Wstack [256,32],
    int j = i & 7, l = (i >> 3) & 63, kn = i >> 9; // Wstack[h*32+k][c]=W[k][h*32+c]
    int kb = kn >> 1, nb2 = kn & 1;
    int krow = kb * 32 + 8 * (l >> 4) + j;         // 0..255
    int h = krow >> 5, kk = krow & 31;
    int c = 16 * nb2 + (l & 15);
    WSb[i] = (u16)bf16r(W[kk * HC + h * 32 + c]);
  }
}

// ---------- K1C (fused): MFMA a-dots + int8 x  ||  replicated histogram + rank ----------
__global__ __launch_bounds__(256) void k1c(
    const float* __restrict__ x, const u16* __restrict__ Wb,
    const u16* __restrict__ Zb, const int* __restrict__ ei,
    unsigned* __restrict__ xqx, unsigned* __restrict__ ascp,
    float* __restrict__ a_d, int* __restrict__ deg4,
    unsigned* __restrict__ dstr, int n, int e, int nbc)
{
  if ((int)blockIdx.x >= nbc) {                    // histogram + rank role
    int bi = (int)blockIdx.x - nbc;
    int r = bi & 3;
    int* dr = deg4 + (size_t)r * n;
    int i = bi * 1024 + (int)threadIdx.x * 4;
    if (i >= e) return;
    const int* dst = ei + e;
    if (i + 3 < e) {
      int4 d4 = *(const int4*)(dst + i);
      unsigned r0 = (unsigned)atomicAdd(&dr[d4.x], 1);
      unsigned r1 = (unsigned)atomicAdd(&dr[d4.y], 1);
      unsigned r2 = (unsigned)atomicAdd(&dr[d4.z], 1);
      unsigned r3 = (unsigned)atomicAdd(&dr[d4.w], 1);
      uint4 o;
      o.x = (unsigned)d4.x | ((unsigned)r << 17) | (r0 << 19);
      o.y = (unsigned)d4.y | ((unsigned)r << 17) | (r1 << 19);
      o.z = (unsigned)d4.z | ((unsigned)r << 17) | (r2 << 19);
      o.w = (unsigned)d4.w | ((unsigned)r << 17) | (r3 << 19);
      *(uint4*)(dstr + i) = o;
    } else {
      for (int k = 0; k < 4 && i + k < e; ++k) {
        int d = dst[i + k];
        unsigned rr = (unsigned)atomicAdd(&dr[d], 1);
        dstr[i + k] = (unsigned)d | ((unsigned)r << 17) | (rr << 19);
      }
    }
    return;
  }
  __shared__ u16 lt[4][16 * 264];                  // per-wave [16 rows][264 halfs]
  int wid = threadIdx.x >> 6, lane = threadIdx.x & 63;
  int q = lane & 15, g = lane >> 4;
  long node0 = (long)((int)blockIdx.x * 4 + wid) * 16;
  if (node0 + 16 > n) node0 = n - 16;              // overlap tail: duplicate identical writes
  u16* L = lt[wid];
  u16* ascp16 = (u16*)ascp;

  // A-frag: x[node0+q][8g..8g+7] -> bf16; keep fp32 copies for quantization
  const float* xr = x + (node0 + q) * CC + 8 * g;
  float4 xa = *(const float4*)xr, xb = *(const float4*)(xr + 4);
  bf16x8 af;
  af[0] = (short)bf16r(xa.x); af[1] = (short)bf16r(xa.y);
  af[2] = (short)bf16r(xa.z); af[3] = (short)bf16r(xa.w);
  af[4] = (short)bf16r(xb.x); af[5] = (short)bf16r(xb.y);
  af[6] = (short)bf16r(xb.z); af[7] = (short)bf16r(xb.w);

  // ---- per-node x absmax over 32 ch (4 lanes share q: xor 16, 32) ----
  float mx = fmaxf(fmaxf(fmaxf(fabsf(xa.x), fabsf(xa.y)), fmaxf(fabsf(xa.z), fabsf(xa.w))),
                   fmaxf(fmaxf(fabsf(xb.x), fabsf(xb.y)), fmaxf(fabsf(xb.z), fabsf(xb.w))));
  mx = fmaxf(mx, __shfl_xor(mx, 16));
  mx = fmaxf(mx, __shfl_xor(mx, 32));
  float rinv = (mx > 0.f) ? 127.f / mx : 0.f;
  u16 sch = f2h(mx * (1.f / 127.f));
  ascp16[((node0 + q) * HH + 2 * g) * 2 + 1]     = sch;
  ascp16[((node0 + q) * HH + 2 * g + 1) * 2 + 1] = sch;
  {
    int q0 = min(max(__float2int_rn(xa.x * rinv), -127), 127) + 128;
    int q1 = min(max(__float2int_rn(xa.y * rinv), -127), 127) + 128;
    int q2 = min(max(__float2int_rn(xa.z * rinv), -127), 127) + 128;
    int q3 = min(max(__float2int_rn(xa.w * rinv), -127), 127) + 128;
    int q4 = min(max(__float2int_rn(xb.x * rinv), -127), 127) + 128;
    int q5 = min(max(__float2int_rn(xb.y * rinv), -127), 127) + 128;
    int q6 = min(max(__float2int_rn(xb.z * rinv), -127), 127) + 128;
    int q7 = min(max(__float2int_rn(xb.w * rinv), -127), 127) + 128;
    uint2 pk;
    pk.x = (unsigned)q0 | ((unsigned)q1 << 8) | ((unsigned)q2 << 16) | ((unsigned)q3 << 24);
    pk.y = (unsigned)q4 | ((unsigned)q5 << 8) | ((unsigned)q6 << 16) | ((unsigned)q7 << 24);
    *(uint2*)(xqx + (node0 + q) * 8 + 2 * g) = pk;
  }

  // ---- xp = x@W into LDS (needed only for the a-dots) ----
#pragma unroll
  for (int nb = 0; nb < 16; ++nb) {
    bf16x8 bf = *(const bf16x8*)(Wb + nb * 512 + lane * 8);
    f32x4 acc = {0.f, 0.f, 0.f, 0.f};
    acc = __builtin_amdgcn_mfma_f32_16x16x32_bf16(af, bf, acc, 0, 0, 0);
    int col = 16 * nb + q;
#pragma unroll
    for (int r = 0; r < 4; ++r)
      L[(4 * g + r) * 264 + col] = (u16)bf16r(acc[r]);
  }
  __syncthreads();

  // a_src/a_dst: [16 nodes,256] x [256,16] via 8 chained mfma
  f32x4 az = {0.f, 0.f, 0.f, 0.f};
#pragma unroll
  for (int kb = 0; kb < 8; ++kb) {
    bf16x8 a2 = *(const bf16x8*)(L + q * 264 + kb * 32 + g * 8);
    bf16x8 zb = *(const bf16x8*)(Zb + kb * 512 + lane * 8);
    az = __builtin_amdgcn_mfma_f32_16x16x32_bf16(a2, zb, az, 0, 0, 0);
  }
  int hq = q & 7;
  if (q < 8) {                                     // a_src -> ascp lo16 (bf16)
#pragma unroll
    for (int r = 0; r < 4; ++r)
      ascp16[((node0 + 4 * g + r) * HH + hq) * 2] = (u16)bf16r(az[r]);
  } else {                                         // a_dst (fp32)
#pragma unroll
    for (int r = 0; r < 4; ++r)
      a_d[(node0 + 4 * g + r) * HH + hq] = az[r];
  }
}

// ---------- scan phase A: per-1024-block sums (over 4 replicas) ----------
__global__ __launch_bounds__(256) void kscanA(const int* __restrict__ deg4,
                                              int* __restrict__ bsum, int n)
{
  __shared__ int ws[4];
  int t = threadIdx.x;
  int i = (int)blockIdx.x * 1024 + t * 4;
  int s = 0;
  if (i + 3 < n) {
#pragma unroll
    for (int r = 0; r < 4; ++r) {
      int4 v = *(const int4*)(deg4 + (size_t)r * n + i);
      s += v.x + v.y + v.z + v.w;
    }
  } else {
    for (int k = 0; k < 4 && i + k < n; ++k)
#pragma unroll
      for (int r = 0; r < 4; ++r) s += deg4[(size_t)r * n + i + k];
  }
#pragma unroll
  for (int mask = 1; mask < 64; mask <<= 1) s += __shfl_xor(s, mask);
  if ((t & 63) == 0) ws[t >> 6] = s;
  __syncthreads();
  if (t == 0) bsum[blockIdx.x] = ws[0] + ws[1] + ws[2] + ws[3];
}

// ---------- scan phase B ----------
__global__ __launch_bounds__(1024) void kscanB(int* __restrict__ bsum, int nb)
{
  __shared__ int wsum[16];
  int t = threadIdx.x, lane = t & 63, wid = t >> 6;
  int v = (t < nb) ? bsum[t] : 0;
  int s = v;
#pragma unroll
  for (int d = 1; d < 64; d <<= 1) { int tt = __shfl_up(s, d); if (lane >= d) s += tt; }
  if (lane == 63) wsum[wid] = s;
  __syncthreads();
  if (wid == 0) {
    int w = (lane < 16) ? wsum[lane] : 0;
#pragma unroll
    for (int d = 1; d < 16; d <<= 1) { int tt = __shfl_up(w, d); if (lane >= d) w += tt; }
    if (lane < 16) wsum[lane] = w;
  }
  __syncthreads();
  int excl = s - v + ((wid > 0) ? wsum[wid - 1] : 0);
  if (t < nb) bsum[t] = excl;
}

// ---------- scan phase C: offs (=rb[0]) + per-replica bases rb[1..3] + degt ----------
__global__ __launch_bounds__(256) void kscanC(const int* __restrict__ deg4,
                                              const int* __restrict__ bsum,
                                              int* __restrict__ rb,
                                              int* __restrict__ degt, int n)
{
  __shared__ int ws[4];
  int t = threadIdx.x, lane = t & 63, wid = t >> 6;
  int i = (int)blockIdx.x * 1024 + t * 4;
  int c0[4] = {0,0,0,0}, c1[4] = {0,0,0,0}, c2[4] = {0,0,0,0}, c3[4] = {0,0,0,0};
  if (i + 3 < n) {
    int4 v0 = *(const int4*)(deg4 + 0 * (size_t)n + i);
    int4 v1 = *(const int4*)(deg4 + 1 * (size_t)n + i);
    int4 v2 = *(const int4*)(deg4 + 2 * (size_t)n + i);
    int4 v3 = *(const int4*)(deg4 + 3 * (size_t)n + i);
    c0[0]=v0.x;c0[1]=v0.y;c0[2]=v0.z;c0[3]=v0.w;
    c1[0]=v1.x;c1[1]=v1.y;c1[2]=v1.z;c1[3]=v1.w;
    c2[0]=v2.x;c2[1]=v2.y;c2[2]=v2.z;c2[3]=v2.w;
    c3[0]=v3.x;c3[1]=v3.y;c3[2]=v3.z;c3[3]=v3.w;
  } else {
    for (int k = 0; k < 4 && i + k < n; ++k) {
      c0[k] = deg4[0 * (size_t)n + i + k];
      c1[k] = deg4[1 * (size_t)n + i + k];
      c2[k] = deg4[2 * (size_t)n + i + k];
      c3[k] = deg4[3 * (size_t)n + i + k];
    }
  }
  int tot[4];
#pragma unroll
  for (int k = 0; k < 4; ++k) tot[k] = c0[k] + c1[k] + c2[k] + c3[k];
  int tsum = tot[0] + tot[1] + tot[2] + tot[3];
  int s = tsum;
#pragma unroll
  for (int d = 1; d < 64; d <<= 1) { int tt = __shfl_up(s, d); if (lane >= d) s += tt; }
  if (lane == 63) ws[wid] = s;
  __syncthreads();
  if (t == 0) {
    int a = ws[0]; ws[0] = 0;
    int b = ws[1]; ws[1] = a; a += b;
    int c = ws[2]; ws[2] = a; a += c;
    ws[3] = a;
  }
  __syncthreads();
  int base = bsum[blockIdx.x] + ws[wid] + (s - tsum);
#pragma unroll
  for (int k = 0; k < 4; ++k) {
    if (i + k < n) {
      int b0 = base;
      rb[0 * (size_t)n + i + k] = b0;
      rb[1 * (size_t)n + i + k] = b0 + c0[k];
      rb[2 * (size_t)n + i + k] = b0 + c0[k] + c1[k];
      rb[3 * (size_t)n + i + k] = b0 + c0[k] + c1[k] + c2[k];
      degt[i + k] = tot[k];
    }
    base += tot[k];
  }
}

// ---------- CSR scatter: rank-based, ATOMIC-FREE, dst-quadrant L2-local writes ----------
__global__ __launch_bounds__(256) void kscatter(
    const int* __restrict__ ei, const unsigned* __restrict__ dstr, int e,
    const int* __restrict__ rb, int* __restrict__ csr, int n)
{
  int oct = (int)blockIdx.x & 3;
  int nsub = (int)gridDim.x >> 2;
  int sub = (int)blockIdx.x >> 2;
  int nper = (n + 3) >> 2;
  int lo = oct * nper, hi = lo + nper;
  int stride = nsub << 10;
  for (int i = (sub * 256 + (int)threadIdx.x) * 4; i < e; i += stride) {
    if (i + 3 < e) {
      uint4 d4 = *(const uint4*)(dstr + i);
      int4 s4 = *(const int4*)(ei + i);
      int dx = d4.x & 0x1ffff, dy = d4.y & 0x1ffff,
          dz = d4.z & 0x1ffff, dw = d4.w & 0x1ffff;
      if (dx >= lo && dx < hi)
        csr[rb[(size_t)((d4.x >> 17) & 3) * n + dx] + (d4.x >> 19)] = s4.x;
      if (dy >= lo && dy < hi)
        csr[rb[(size_t)((d4.y >> 17) & 3) * n + dy] + (d4.y >> 19)] = s4.y;
      if (dz >= lo && dz < hi)
        csr[rb[(size_t)((d4.z >> 17) & 3) * n + dz] + (d4.z >> 19)] = s4.z;
      if (dw >= lo && dw < hi)
        csr[rb[(size_t)((d4.w >> 17) & 3) * n + dw] + (d4.w >> 19)] = s4.w;
    } else {
      for (int k = 0; k < 4 && i + k < e; ++k) {
        unsigned dv = dstr[i + k];
        int d = dv & 0x1ffff;
        if (d >= lo && d < hi)
          csr[rb[(size_t)((dv >> 17) & 3) * n + d] + (dv >> 19)] = ei[i + k];
      }
    }
  }
}

// ---------- KAGG: aggregate RAW x (int8, 32B/row) with per-head attn; agg bf16 out ----------
__global__ __launch_bounds__(256) void kagg(
    const int* __restrict__ csr, const int* __restrict__ offs,
    const int* __restrict__ degt,
    const unsigned* __restrict__ ascp, const float* __restrict__ a_d,
    const unsigned* __restrict__ xqx, unsigned* __restrict__ agg32, int n)
{
  int lane = threadIdx.x & 63;
  int wid  = threadIdx.x >> 6;
  int base = ((int)blockIdx.x * 4 + wid) * 4;      // 4 nodes per wave
  int eg = lane >> 3, ha = lane & 7;
  int hb = eg;
  int c4 = lane & 7;

  for (int t = 0; t < 4; ++t) {
    int node = base + t;
    if (node >= n) return;
    int start = offs[node];
    int dg = degt[node];
    unsigned aw_self = ascp[(size_t)node * HH + ha];
    float ad_a  = a_d[(size_t)node * HH + ha];
    float aself = leaky(bflo(aw_self) + ad_a);

    float acc0 = 0.f, acc1 = 0.f, acc2 = 0.f, acc3 = 0.f;
    float dnA = 0.f, osA = 0.f;

    for (int j0 = 0; j0 < dg; j0 += 8) {
      int cnt = dg - j0; if (cnt > 8) cnt = 8;
      int idx = j0 + eg;
      int srcl = 0; float pw = 0.f;
      if (idx < dg) {
        srcl = csr[start + idx];
        unsigned av = ascp[(size_t)srcl * HH + ha];
        float al = leaky(bflo(av) + ad_a);
        float p  = __expf(al - aself);
        pw = p * h2f(av >> 16);                    // p * xscale_src
        dnA += p; osA += pw;
      }
      if (cnt == 8) {
#pragma unroll
        for (int j = 0; j < 8; ++j) {
          int sl = (j << 3) + hb;                  // srcl replicated across head lanes
          float wt = __shfl(pw, sl);
          int s = __shfl(srcl, sl);
          unsigned w = xqx[(size_t)s * 8 + c4];
          acc0 = fmaf(ub0(w), wt, acc0);
          acc1 = fmaf(ub1(w), wt, acc1);
          acc2 = fmaf(ub2(w), wt, acc2);
          acc3 = fmaf(ub3(w), wt, acc3);
        }
      } else {
        for (int j = 0; j < cnt; ++j) {
          int sl = (j << 3) + hb;
          float wt = __shfl(pw, sl);
          int s = __shfl(srcl, sl);
          unsigned w = xqx[(size_t)s * 8 + c4];
          acc0 = fmaf(ub0(w), wt, acc0);
          acc1 = fmaf(ub1(w), wt, acc1);
          acc2 = fmaf(ub2(w), wt, acc2);
          acc3 = fmaf(ub3(w), wt, acc3);
        }
      }
    }

    // reduce dn/osum over edge-slot dim (eg): after this, value is per-head ha
    float dnH = dnA, osH = osA;
    dnH += __shfl_xor(dnH, 8);  osH += __shfl_xor(osH, 8);
    dnH += __shfl_xor(dnH, 16); osH += __shfl_xor(osH, 16);
    dnH += __shfl_xor(dnH, 32); osH += __shfl_xor(osH, 32);
    float dnB = __shfl(dnH, hb);
    float osB = __shfl(osH, hb);
    float scB = __shfl(h2f(aw_self >> 16), hb);    // xscale_node (replicated)

    // self loop: p = 1
    {
      unsigned w = xqx[(size_t)node * 8 + c4];
      dnB += 1.f; osB += scB;
      acc0 = fmaf(ub0(w), scB, acc0);
      acc1 = fmaf(ub1(w), scB, acc1);
      acc2 = fmaf(ub2(w), scB, acc2);
      acc3 = fmaf(ub3(w), scB, acc3);
    }

    float corr = -128.f * osB;
    float inv = 0.125f / dnB;                      // fold 1/8 head-mean here
    acc0 = (acc0 + corr) * inv;
    acc1 = (acc1 + corr) * inv;
    acc2 = (acc2 + corr) * inv;
    acc3 = (acc3 + corr) * inv;
    uint2 pk;
    pk.x = bf16r(acc0) | (bf16r(acc1) << 16);
    pk.y = bf16r(acc2) | (bf16r(acc3) << 16);
    *(uint2*)(agg32 + (size_t)node * 128 + hb * 16 + c4 * 2) = pk;
  }
}

// ---------- K5M: MFMA tail — og = agg@Wstack, + x + bg, LN1 + FFN(mfma) + LN2 ----------
__global__ __launch_bounds__(256) void k5m(
    const u16* __restrict__ agg16, const float* __restrict__ x,
    const float* __restrict__ bg, const u16* __restrict__ WSb,
    const u16* __restrict__ V1b, const u16* __restrict__ V2b,
    const float* __restrict__ b1, const float* __restrict__ b2,
    const float* __restrict__ g1, const float* __restrict__ be1,
    const float* __restrict__ g2, const float* __restrict__ be2,
    float* __restrict__ out, int n)
{
  __shared__ u16   lh[4][16 * 40];
  __shared__ u16   lf[4][16 * 136];
  __shared__ float lo[4][16 * 36];
  int wid = threadIdx.x >> 6, lane = threadIdx.x & 63;
  int q = lane & 15, g = lane >> 4;
  long node0 = (long)((int)blockIdx.x * 4 + wid) * 16;
  if (node0 + 16 > n) node0 = n - 16;
  u16* LH = lh[wid]; u16* LF = lf[wid]; float* LO = lo[wid];

  // stage x + bg cooperatively
  {
    int row = lane >> 2, off = (lane & 3) * 8;
    const float* x8 = x + (node0 + row) * CC + off;
    float4 c0 = *(const float4*)x8, c1 = *(const float4*)(x8 + 4);
    float4 bg0 = *(const float4*)(bg + off), bg1 = *(const float4*)(bg + off + 4);
    float4 s0 = make_float4(c0.x + bg0.x, c0.y + bg0.y, c0.z + bg0.z, c0.w + bg0.w);
    float4 s1 = make_float4(c1.x + bg1.x, c1.y + bg1.y, c1.z + bg1.z, c1.w + bg1.w);
    *(float4*)(LO + row * 36 + off)     = s0;
    *(float4*)(LO + row * 36 + off + 4) = s1;
  }
  __syncthreads();

  // og = agg @ Wstack  ([16,256] x [256,32]) then LO += og
  {
    f32x4 a20 = {0.f, 0.f, 0.f, 0.f}, a21 = {0.f, 0.f, 0.f, 0.f};
#pragma unroll
    for (int kb = 0; kb < 8; ++kb) {
      bf16x8 af = *(const bf16x8*)(agg16 + (node0 + q) * 256 + kb * 32 + g * 8);
      bf16x8 w0 = *(const bf16x8*)(WSb + (kb * 2 + 0) * 512 + lane * 8);
      bf16x8 w1v = *(const bf16x8*)(WSb + (kb * 2 + 1) * 512 + lane * 8);
      a20 = __builtin_amdgcn_mfma_f32_16x16x32_bf16(af, w0, a20, 0, 0, 0);
      a21 = __builtin_amdgcn_mfma_f32_16x16x32_bf16(af, w1v, a21, 0, 0, 0);
    }
#pragma unroll
    for (int r = 0; r < 4; ++r) {
      LO[(4 * g + r) * 36 + q]      += a20[r];
      LO[(4 * g + r) * 36 + 16 + q] += a21[r];
    }
  }
  __syncthreads();

  float hv[32];
  if (lane < 16) {
#pragma unroll
    for (int i = 0; i < 8; ++i) {
      float4 t = *(const float4*)(LO + q * 36 + i * 4);
      hv[4*i] = t.x; hv[4*i+1] = t.y; hv[4*i+2] = t.z; hv[4*i+3] = t.w;
    }
    float mu = 0.f;
#pragma unroll
    for (int c = 0; c < 32; ++c) mu += hv[c];
    mu *= (1.f / 32.f);
    float var = 0.f;
#pragma unroll
    for (int c = 0; c < 32; ++c) { float t = hv[c] - mu; var = fmaf(t, t, var); }
    float rs = rsqrtf(var * (1.f / 32.f) + LNEPS);
#pragma unroll
    for (int c = 0; c < 32; ++c) hv[c] = (hv[c] - mu) * rs * g1[c] + be1[c];
    uint* dst = (uint*)(LH + q * 40);
#pragma unroll
    for (int i = 0; i < 16; ++i)
      dst[i] = bf16r(hv[2*i]) | (bf16r(hv[2*i+1]) << 16);
  }
  __syncthreads();

  bf16x8 ah = *(const bf16x8*)(LH + q * 40 + g * 8);
#pragma unroll
  for (int nb = 0; nb < 8; ++nb) {
    bf16x8 v1 = *(const bf16x8*)(V1b + nb * 512 + lane * 8);
    f32x4 acc = {0.f, 0.f, 0.f, 0.f};
    acc = __builtin_amdgcn_mfma_f32_16x16x32_bf16(ah, v1, acc, 0, 0, 0);
    int col = 16 * nb + q;
    float bias = b1[col];
#pragma unroll
    for (int r = 0; r < 4; ++r) {
      float f = fmaxf(acc[r] + bias, 0.f);
      LF[(4 * g + r) * 136 + col] = (u16)bf16r(f);
    }
  }
  __syncthreads();

  f32x4 a20 = {0.f, 0.f, 0.f, 0.f}, a21 = {0.f, 0.f, 0.f, 0.f};
#pragma unroll
  for (int kb = 0; kb < 4; ++kb) {
    bf16x8 af2 = *(const bf16x8*)(LF + q * 136 + kb * 32 + g * 8);
    bf16x8 v20 = *(const bf16x8*)(V2b + (kb * 2 + 0) * 512 + lane * 8);
    bf16x8 v21 = *(const bf16x8*)(V2b + (kb * 2 + 1) * 512 + lane * 8);
    a20 = __builtin_amdgcn_mfma_f32_16x16x32_bf16(af2, v20, a20, 0, 0, 0);
    a21 = __builtin_amdgcn_mfma_f32_16x16x32_bf16(af2, v21, a21, 0, 0, 0);
  }
  __syncthreads();
#pragma unroll
  for (int r = 0; r < 4; ++r) {
    LO[(4 * g + r) * 36 + q]      = a20[r];
    LO[(4 * g + r) * 36 + 16 + q] = a21[r];
  }
  __syncthreads();

  if (lane < 16) {
    float ov[32];
#pragma unroll
    for (int i = 0; i < 8; ++i) {
      float4 t = *(const float4*)(LO + q * 36 + i * 4);
      ov[4*i] = t.x; ov[4*i+1] = t.y; ov[4*i+2] = t.z; ov[4*i+3] = t.w;
    }
#pragma unroll
    for (int c = 0; c < 32; ++c) ov[c] += b2[c] + hv[c];
    float mu2 = 0.f;
#pragma unroll
    for (int c = 0; c < 32; ++c) mu2 += ov[c];
    mu2 *= (1.f / 32.f);
    float var2 = 0.f;
#pragma unroll
    for (int c = 0; c < 32; ++c) { float t = ov[c] - mu2; var2 = fmaf(t, t, var2); }
    float rs2 = rsqrtf(var2 * (1.f / 32.f) + LNEPS);
    float* op = out + (node0 + q) * CC;
#pragma unroll
    for (int i = 0; i < 8; ++i) {
      float4 o;
      o.x = (ov[4*i]   - mu2) * rs2 * g2[4*i]   + be2[4*i];
      o.y = (ov[4*i+1] - mu2) * rs2 * g2[4*i+1] + be2[4*i+1];
      o.z = (ov[4*i+2] - mu2) * rs2 * g2[4*i+2] + be2[4*i+2];
      o.w = (ov[4*i+3] - mu2) * rs2 * g2[4*i+3] + be2[4*i+3];
      *(float4*)(op + i * 4) = o;
    }
  }
}

// ---------- launch ----------
extern "C" void kernel_launch(void* const* d_in, const int* in_sizes, int n_in,
                              void* d_out, int out_size, void* d_ws, size_t ws_size,
                              hipStream_t stream)
{
  const float* x    = (const float*)d_in[0];
  const int*   ei   = (const int*)d_in[1];
  const float* W    = (const float*)d_in[2];
  const float* atts = (const float*)d_in[3];
  const float* attd = (const float*)d_in[4];
  const float* bg   = (const float*)d_in[5];
  const float* w1   = (const float*)d_in[6];
  const float* b1   = (const float*)d_in[7];
  const float* w2   = (const float*)d_in[8];
  const float* b2   = (const float*)d_in[9];
  const float* g1   = (const float*)d_in[10];
  const float* be1  = (const float*)d_in[11];
  const float* g2   = (const float*)d_in[12];
  const float* be2  = (const float*)d_in[13];

  int n = in_sizes[0] / CC;
  int e = in_sizes[1] / 2;

  uint8_t* ws = (uint8_t*)d_ws;
  size_t o = 0;
  unsigned* xqx = (unsigned*)(ws + o); o += (size_t)n * 32;      // int8 x rows, 32B/node
  unsigned* ascp = (unsigned*)(ws + o); o += (size_t)n * HH * 4; // bf16 a_src|fp16 xscale
  float* a_d = (float*)(ws + o); o += (size_t)n * HH * 4;
  unsigned* agg32 = (unsigned*)(ws + o); o += (size_t)n * 512;   // bf16 agg [N,256]
  int* deg4   = (int*)(ws + o); o += (size_t)n * 4 * 4;
  int* rb     = (int*)(ws + o); o += (size_t)n * 4 * 4;
  int* degt   = (int*)(ws + o); o += (size_t)n * 4;
  unsigned* dstr = (unsigned*)(ws + o); o += (size_t)e * 4;
  int* csr    = (int*)(ws + o); o += (size_t)e * 4;
  int* bsum   = (int*)(ws + o); o += 4096;
  u16* Wb  = (u16*)(ws + o); o += 16 * 512 * 2;
  u16* Zb  = (u16*)(ws + o); o += 8 * 512 * 2;
  u16* V1b = (u16*)(ws + o); o += 8 * 512 * 2;
  u16* V2b = (u16*)(ws + o); o += 8 * 512 * 2;
  u16* WSb = (u16*)(ws + o); o += 16 * 512 * 2;

  (void)hipMemsetAsync(deg4, 0, (size_t)n * 4 * 4, stream);

  int nwaves = (n + 15) / 16;
  int nbc   = (nwaves + 3) / 4;
  int nb_e4 = (e + 1023) / 1024;
  int nb_s  = (n + 1023) / 1024;
  int nb_ag = (n + 15) / 16;        // 4 waves x 4 nodes = 16 nodes per block

  klayout <<<16, 256, 0, stream>>>(W, atts, attd, w1, w2, Wb, Zb, V1b, V2b, WSb);
  k1c     <<<nbc + nb_e4, 256, 0, stream>>>(x, Wb, Zb, ei, xqx, ascp, a_d, deg4,
                                            dstr, n, e, nbc);
  kscanA  <<<nb_s, 256, 0, stream>>>(deg4, bsum, n);
  kscanB  <<<1, 1024, 0, stream>>>(bsum, nb_s);
  kscanC  <<<nb_s, 256, 0, stream>>>(deg4, bsum, rb, degt, n);
  kscatter<<<512, 256, 0, stream>>>(ei, dstr, e, rb, csr, n);
  kagg    <<<nb_ag, 256, 0, stream>>>(csr, rb, degt, ascp, a_d, xqx, agg32, n);
  k5m     <<<nbc, 256, 0, stream>>>((const u16*)agg32, x, bg, WSb, V1b, V2b,
                                    b1, b2, g1, be1, g2, be2, (float*)d_out, n);
}